// Round 9
// baseline (308.682 us; speedup 1.0000x reference)
//
#include <hip/hip_runtime.h>
#include <hip/hip_bf16.h>

#define N0   3000
#define E0   48000
#define K1N  1500
#define K2N  750
#define HID  128
#define CAP  128
#define LD1  1536  // padded leading dim for A1
#define LD2  768   // padded leading dim for A2/Ac
#define BM   32    // row-tile for k_yw2
#define ATS  36    // transposed X-tile stride (BM+4, bank-spread)

__device__ __forceinline__ unsigned fkey(float f) {
  unsigned u = __float_as_uint(f);
  return (u & 0x80000000u) ? ~u : (u | 0x80000000u);
}
__device__ __forceinline__ float inv_fkey(unsigned u) {
  unsigned v = (u & 0x80000000u) ? (u & 0x7FFFFFFFu) : ~u;
  return __uint_as_float(v);
}

// ---------------- workspace layout (float units) ----------------
constexpr size_t F_A1    = 0;                          // K1N*LD1
constexpr size_t F_SCR   = F_A1 + (size_t)K1N * LD1;   // Ac = K1N*LD2
constexpr size_t SCR_SZ  = 1155072;                    // >= K1N*LD2 (1,152,000)
constexpr size_t F_A2    = F_SCR + SCR_SZ;             // K2N*LD2
constexpr size_t F_YSC   = F_A2 + (size_t)K2N * LD2;   // N0*HID
constexpr size_t F_H0    = F_YSC + (size_t)N0 * HID;   // N0*HID
constexpr size_t F_H1    = F_H0 + (size_t)N0 * HID;    // K1N*HID
constexpr size_t F_H2    = F_H1 + (size_t)K1N * HID;   // K2N*HID
constexpr size_t F_U1    = F_H2 + (size_t)K2N * HID;   // (hole, kept for layout)
constexpr size_t F_U1B   = F_U1 + (size_t)K1N * HID;   // K1N*HID
constexpr size_t F_YF    = F_U1B + (size_t)K1N * HID;  // N0*3
constexpr size_t F_SCORE = F_YF + (size_t)N0 * 3;      // N0
constexpr size_t F_GATE1 = F_SCORE + N0;               // K1N  } contiguous zero fill
constexpr size_t F_GATE2 = F_GATE1 + K1N;              // K2N  }
constexpr size_t F_DIS0  = F_GATE2 + K2N;              // (unused)
constexpr size_t F_DIS1  = F_DIS0 + N0;                // K1N
constexpr size_t F_DIS2  = F_DIS1 + K1N;               // K2N
constexpr size_t F_PERM1 = F_DIS2 + K2N;               // K1N (int) } contiguous 0 fill
constexpr size_t F_PERM2 = F_PERM1 + K1N;              // K2N (int) }
constexpr size_t F_INV1  = F_PERM2 + K2N;              // N0  (int) } contiguous -1 fill
constexpr size_t F_INV2  = F_INV1 + N0;                // K1N (int) }
constexpr size_t F_CNTI  = F_INV2 + K1N;               // N0  (int) } contiguous 0 fill
constexpr size_t F_CNTO  = F_CNTI + N0;                // N0  (int) }
constexpr size_t F_SELF  = F_CNTO + N0;                // N0  (int) }
constexpr size_t F_CI    = F_SELF + N0;                // N0*CAP (int)
constexpr size_t F_CO    = F_CI + (size_t)N0 * CAP;    // N0*CAP (int)
constexpr size_t F_END   = F_CO + (size_t)N0 * CAP;

// ---------------- init: all fills fused (1 dispatch) ----------------
__global__ void k_init(float* __restrict__ A1, float* __restrict__ gate,
                       int* __restrict__ perm, int* __restrict__ inv,
                       int* __restrict__ cnt, float* __restrict__ outlab) {
  int i = blockIdx.x * blockDim.x + threadIdx.x, st = gridDim.x * blockDim.x;
  for (int j = i; j < K1N * LD1; j += st) A1[j] = 0.0f;
  for (int j = i; j < K1N + K2N; j += st) gate[j] = 0.0f;
  for (int j = i; j < K1N + K2N; j += st) perm[j] = 0;
  for (int j = i; j < N0 + K1N; j += st) inv[j] = -1;
  for (int j = i; j < 3 * N0; j += st) cnt[j] = 0;
  for (int j = i; j < N0 * 29; j += st) outlab[j] = 0.0f;
}

// Build per-node edge lists: col_in[d] = srcs of non-self in-edges, col_out[s] = dsts.
__global__ void k_count(const int* __restrict__ ei, int* cnt_in, int* cnt_out, int* selfc,
                        int* col_in, int* col_out) {
  int e = blockIdx.x * blockDim.x + threadIdx.x;
  if (e >= E0) return;
  int s = ei[e], d = ei[E0 + e];
  if (s == d) { atomicAdd(&selfc[d], 1); return; }
  int a = atomicAdd(&cnt_in[d], 1);
  if (a < CAP) col_in[d * CAP + a] = s;
  int b = atomicAdd(&cnt_out[s], 1);
  if (b < CAP) col_out[s * CAP + b] = d;
}

// Ysc[row][f] = scale(row) * sum_k Xeff[src(row)][k] * Wm[k][f]
// Xeff = X (+ X2[inv2c[row]] if combine). scale = (dis ? dis : 1/sqrt(cnt+self+2)) * gate.
__global__ __launch_bounds__(256) void k_yw2(const float* __restrict__ X,
                                             const float* __restrict__ X2,
                                             const int* __restrict__ inv2c,
                                             int Kin, int nsrc, int n,
                                             const float* __restrict__ Wm,
                                             const int* __restrict__ perm,
                                             const float* __restrict__ gate,
                                             const float* __restrict__ dis,
                                             const int* __restrict__ cntd,
                                             const int* __restrict__ selfd,
                                             float* __restrict__ Ysc) {
  __shared__ float Wt[32 * HID];   // 16 KB, [kk][f]
  __shared__ float Xt[32 * ATS];   // 4.6 KB, [kk][row] transposed
  int t = threadIdx.x;
  int r0 = blockIdx.x * BM;
  int f4 = (t & 31) * 4;
  int rg = t >> 5;                 // 0..7 -> rows r0 + rg*4 + {0..3}
  float4 acc0 = {0,0,0,0}, acc1 = {0,0,0,0}, acc2 = {0,0,0,0}, acc3 = {0,0,0,0};
  for (int kb = 0; kb < Kin; kb += 32) {
    {
      const float4* src = (const float4*)(Wm + (size_t)kb * HID);
      float4* dst = (float4*)Wt;
#pragma unroll
      for (int i = 0; i < 4; ++i) dst[i * 256 + t] = src[i * 256 + t];
    }
    {
      int j = t >> 3;
      int k4 = (t & 7) * 4;
      int r = r0 + j;
      int src_row = (r < n) ? r : (n - 1);
      if (perm) {
        int s = perm[src_row];
        if (s < 0) s = 0;
        if (s >= nsrc) s = nsrc - 1;
        src_row = s;
      }
      float4 xv = *(const float4*)(X + (size_t)src_row * Kin + kb + k4);
      if (X2) {
        int ii = inv2c[src_row];
        if (ii >= 0 && ii < K2N) {
          float4 x2 = *(const float4*)(X2 + (size_t)ii * Kin + kb + k4);
          xv.x += x2.x; xv.y += x2.y; xv.z += x2.z; xv.w += x2.w;
        }
      }
      Xt[(k4 + 0) * ATS + j] = xv.x;
      Xt[(k4 + 1) * ATS + j] = xv.y;
      Xt[(k4 + 2) * ATS + j] = xv.z;
      Xt[(k4 + 3) * ATS + j] = xv.w;
    }
    __syncthreads();
#pragma unroll 4
    for (int kk = 0; kk < 32; ++kk) {
      float4 y = *(const float4*)&Wt[kk * HID + f4];
      float4 a = *(const float4*)&Xt[kk * ATS + rg * 4];
      acc0.x += a.x * y.x; acc0.y += a.x * y.y; acc0.z += a.x * y.z; acc0.w += a.x * y.w;
      acc1.x += a.y * y.x; acc1.y += a.y * y.y; acc1.z += a.y * y.z; acc1.w += a.y * y.w;
      acc2.x += a.z * y.x; acc2.y += a.z * y.y; acc2.z += a.z * y.z; acc2.w += a.z * y.w;
      acc3.x += a.w * y.x; acc3.y += a.w * y.y; acc3.z += a.w * y.z; acc3.w += a.w * y.w;
    }
    __syncthreads();
  }
  int r = r0 + rg * 4;
  float4* accs[4] = {&acc0, &acc1, &acc2, &acc3};
#pragma unroll
  for (int j = 0; j < 4; ++j) {
    int row = r + j;
    if (row >= n) continue;
    float g = gate ? gate[row] : 1.0f;
    float d = dis ? dis[row] : (1.0f / sqrtf((float)(cntd[row] + selfd[row] + 2)));
    float s = d * g;
    float4 a = *accs[j];
    *(float4*)&Ysc[(size_t)row * HID + f4] = make_float4(s * a.x, s * a.y, s * a.z, s * a.w);
  }
}

// Level-0 sparse GCN + fused score — single wave, 2 features/thread, no barriers.
__global__ __launch_bounds__(64) void k_gcn_sparse(const float* __restrict__ Ysc,
                                                   const int* __restrict__ cnt_in,
                                                   const int* __restrict__ col_in,
                                                   const int* __restrict__ selfc,
                                                   const float* __restrict__ bias,
                                                   const float* __restrict__ p,
                                                   float* __restrict__ H,
                                                   float* __restrict__ score) {
  int d = blockIdx.x, t = threadIdx.x;
  int f = 2 * t;
  int cntu = cnt_in[d];
  int cnt = cntu > CAP ? CAP : cntu;
  float sc_self = 2.0f + (float)selfc[d];
  float2 ys = *(const float2*)&Ysc[(size_t)d * HID + f];
  float ax = sc_self * ys.x, ay = sc_self * ys.y;
  for (int e = 0; e < cnt; ++e) {
    int s = col_in[d * CAP + e];
    float2 v = *(const float2*)&Ysc[(size_t)s * HID + f];
    ax += v.x; ay += v.y;
  }
  float d0 = 1.0f / sqrtf((float)(cntu + selfc[d] + 2));
  float2 bv = *(const float2*)&bias[f];
  float h0v = tanhf(d0 * ax + bv.x);
  float h1v = tanhf(d0 * ay + bv.y);
  *(float2*)&H[(size_t)d * HID + f] = make_float2(h0v, h1v);
  float2 pv = *(const float2*)&p[f];
  float sc = h0v * pv.x + h1v * pv.y;
  float pn = pv.x * pv.x + pv.y * pv.y;
  for (int off = 32; off > 0; off >>= 1) {
    sc += __shfl_down(sc, off);
    pn += __shfl_down(pn, off);
  }
  if (t == 0) score[d] = tanhf(sc * (1.0f / sqrtf(pn)));
}

// Top-K, one 256-thread block. Radix-select with hierarchical set compaction
// between passes; final index-ordered ballot compaction (verified) over score[].
__global__ __launch_bounds__(256) void k_topk(const float* __restrict__ score, int n, int K,
                                              int* __restrict__ perm, float* __restrict__ gatec,
                                              int* __restrict__ inv) {
  __shared__ unsigned setA[N0];
  __shared__ unsigned setB[N0];
  __shared__ int hist[256];
  __shared__ int sscan[257];
  __shared__ unsigned pfx_sh;
  __shared__ int rem_sh;
  __shared__ int cnt_sh;
  int t = threadIdx.x;
  for (int i = t; i < n; i += 256) setA[i] = fkey(score[i]);
  __syncthreads();

  unsigned prefix = 0; int rem = K; int m = n;
  unsigned* cur = setA; unsigned* nxt = setB;
  for (int pass = 3; pass >= 0; --pass) {
    hist[t] = 0;
    __syncthreads();
    for (int i = t; i < m; i += 256) atomicAdd(&hist[(cur[i] >> (pass * 8)) & 255], 1);
    __syncthreads();
    sscan[t] = hist[t];
    if (t == 0) sscan[256] = 0;
    __syncthreads();
    for (int off = 1; off < 256; off <<= 1) {
      int add = (t + off < 256) ? sscan[t + off] : 0;
      __syncthreads();
      sscan[t] += add;
      __syncthreads();
    }
    if (sscan[t] >= rem && sscan[t + 1] < rem) {
      pfx_sh = prefix | ((unsigned)t << (pass * 8));
      rem_sh = rem - sscan[t + 1];
    }
    __syncthreads();
    prefix = pfx_sh; rem = rem_sh;
    if (pass > 0) {
      // compact survivors (byte==selected digit) cur -> nxt; order irrelevant (counts only)
      unsigned dg = (prefix >> (pass * 8)) & 255u;
      if (t == 0) cnt_sh = 0;
      __syncthreads();
      int lane = t & 63;
      unsigned long long below = (lane == 0) ? 0ull : (~0ull >> (64 - lane));
      for (int c0 = 0; c0 < m; c0 += 256) {
        int i = c0 + t;
        unsigned u = (i < m) ? cur[i] : 0u;
        bool match = (i < m) && (((u >> (pass * 8)) & 255u) == dg);
        unsigned long long mm = __ballot(match);
        int cw = (int)__popcll(mm);
        int basew = 0;
        if (lane == 0 && cw) basew = atomicAdd(&cnt_sh, cw);
        basew = __shfl(basew, 0);
        if (match) nxt[basew + (int)__popcll(mm & below)] = u;
      }
      __syncthreads();
      m = cnt_sh;
      unsigned* tmp = cur; cur = nxt; nxt = tmp;
    }
  }
  unsigned uthr = prefix;
  int c_gt = K - rem;
  if (t >= 64) return;
  int lane = t;
  unsigned long long below = (lane == 0) ? 0ull : (~0ull >> (64 - lane));
  int base_gt = 0, base_eq = 0;
  for (int chunk = 0; chunk < n; chunk += 64) {
    int i = chunk + lane;
    bool valid = (i < n);
    unsigned u = valid ? fkey(score[i]) : 0u;
    bool isgt = valid && (u > uthr);
    bool iseq = valid && (u == uthr);
    unsigned long long mg = __ballot(isgt);
    unsigned long long me = __ballot(iseq);
    if (isgt) {
      int pos = base_gt + (int)__popcll(mg & below);
      perm[pos] = i; gatec[pos] = inv_fkey(u); inv[i] = pos;
    } else if (iseq) {
      int er = base_eq + (int)__popcll(me & below);
      if (er < rem) { int pos = c_gt + er; perm[pos] = i; gatec[pos] = inv_fkey(u); inv[i] = pos; }
    }
    base_gt += (int)__popcll(mg);
    base_eq += (int)__popcll(me);
  }
}

// A0 augment restricted to selected nodes, fused with the +2*A' term.
__global__ void k_pairs(const int* __restrict__ cnt_in, const int* __restrict__ col_in,
                        const int* __restrict__ cnt_out, const int* __restrict__ col_out,
                        const int* __restrict__ inv, float* __restrict__ A1) {
  __shared__ int outl[CAP], inl[CAP], invo[CAP], invi[CAP];
  int k = blockIdx.x, t = threadIdx.x;
  int no = cnt_out[k]; if (no > CAP) no = CAP;
  int ni = cnt_in[k];  if (ni > CAP) ni = CAP;
  if (t < no) { int i = col_out[k * CAP + t]; outl[t] = i; invo[t] = inv[i]; }
  if (t < ni) { int j = col_in[k * CAP + t];  inl[t] = j;  invi[t] = inv[j]; }
  __syncthreads();
  int invk = inv[k];
  if (t < ni && invk >= 0) {
    int jj = invi[t];
    if (jj >= 0) atomicAdd(&A1[(size_t)invk * LD1 + jj], 2.0f);   // edge term (2*A')
  }
  for (int a = t; a < no; a += blockDim.x) {
    int i = outl[a], ii = invo[a];
    if (ii < 0) continue;
    for (int b = 0; b < ni; ++b) {
      int jj = invi[b];
      if (jj >= 0 && i != inl[b]) atomicAdd(&A1[(size_t)ii * LD1 + jj], 1.0f);
    }
  }
}

__global__ void k_rowsum(const float* __restrict__ A, int n, int ld, float* __restrict__ dis) {
  __shared__ float red[256];
  int r = blockIdx.x, t = threadIdx.x;
  float acc = 0.0f;
  for (int c = t; c < n; c += 256) acc += A[(size_t)r * ld + c];
  red[t] = acc; __syncthreads();
  for (int s = 128; s > 0; s >>= 1) { if (t < s) red[t] += red[t + s]; __syncthreads(); }
  if (t == 0) dis[r] = 1.0f / sqrtf(red[0] + 2.0f);
}

// Column compaction: Ac[k][b] = A1[k][perm2[b]]  (b < K2N, else 0); grid = K1N rows
__global__ __launch_bounds__(256) void k_cmp(const float* __restrict__ A1,
                                             const int* __restrict__ perm2,
                                             float* __restrict__ Ac) {
  __shared__ int q[K2N];
  int k = blockIdx.x, t = threadIdx.x;
  for (int i = t; i < K2N; i += 256) {
    int v = perm2[i];
    if (v < 0) v = 0;
    if (v >= K1N) v = K1N - 1;
    q[i] = v;
  }
  __syncthreads();
  const float* row = A1 + (size_t)k * LD1;
  float* dst = Ac + (size_t)k * LD2;
  for (int b = t; b < LD2; b += 256) dst[b] = (b < K2N) ? row[q[b]] : 0.0f;
}

// A2[a][b] = (b!=a) ? sum_k A1[qa][k]*Ac[k][b] + 2*A1[qa][perm2[b]] : 0
// + fused dis2[a] = 1/sqrt(rowsum(A2[a]) + 2)  (integer-exact)
__global__ __launch_bounds__(256) void k_sq2(const float* __restrict__ A1,
                                             const float* __restrict__ Ac,
                                             const int* __restrict__ perm2,
                                             float* __restrict__ A2,
                                             float* __restrict__ dis2) {
  __shared__ int klist[K1N];
  __shared__ float wlist[K1N];
  __shared__ int nnz_sh;
  __shared__ float wred[4];
  int a = blockIdx.x, t = threadIdx.x;
  int qa = perm2[a];
  if (qa < 0) qa = 0;
  if (qa >= K1N) qa = K1N - 1;
  if (t == 0) nnz_sh = 0;
  __syncthreads();
  const float* arow = A1 + (size_t)qa * LD1;
  for (int c = t; c < K1N; c += 256) {
    float w = arow[c];
    if (w != 0.0f) { int p = atomicAdd(&nnz_sh, 1); klist[p] = c; wlist[p] = w; }
  }
  __syncthreads();
  int nnz = nnz_sh;
  int c0 = t * 4;
  bool active = (c0 < LD2);
  float4 acc = make_float4(0.f, 0.f, 0.f, 0.f);
  int p = 0;
  for (; p + 4 <= nnz; p += 4) {
    int k0 = klist[p], k1 = klist[p + 1], k2 = klist[p + 2], k3 = klist[p + 3];
    float w0 = wlist[p], w1 = wlist[p + 1], w2 = wlist[p + 2], w3 = wlist[p + 3];
    if (active) {
      float4 v0 = *(const float4*)&Ac[(size_t)k0 * LD2 + c0];
      float4 v1 = *(const float4*)&Ac[(size_t)k1 * LD2 + c0];
      float4 v2 = *(const float4*)&Ac[(size_t)k2 * LD2 + c0];
      float4 v3 = *(const float4*)&Ac[(size_t)k3 * LD2 + c0];
      acc.x += w0 * v0.x; acc.y += w0 * v0.y; acc.z += w0 * v0.z; acc.w += w0 * v0.w;
      acc.x += w1 * v1.x; acc.y += w1 * v1.y; acc.z += w1 * v1.z; acc.w += w1 * v1.w;
      acc.x += w2 * v2.x; acc.y += w2 * v2.y; acc.z += w2 * v2.z; acc.w += w2 * v2.w;
      acc.x += w3 * v3.x; acc.y += w3 * v3.y; acc.z += w3 * v3.z; acc.w += w3 * v3.w;
    }
  }
  for (; p < nnz; ++p) {
    int k = klist[p]; float w = wlist[p];
    if (active) {
      float4 v = *(const float4*)&Ac[(size_t)k * LD2 + c0];
      acc.x += w * v.x; acc.y += w * v.y; acc.z += w * v.z; acc.w += w * v.w;
    }
  }
  float rsum = 0.0f;
  if (active) {
    float accv[4] = {acc.x, acc.y, acc.z, acc.w};
    float outv[4];
#pragma unroll
    for (int j = 0; j < 4; ++j) {
      int col = c0 + j;
      float v = 0.0f;
      if (col < K2N && col != a) {
        int qb = perm2[col];
        if (qb < 0) qb = 0;
        if (qb >= K1N) qb = K1N - 1;
        v = accv[j] + 2.0f * arow[qb];
      }
      outv[j] = v;
      rsum += v;
    }
    *(float4*)&A2[(size_t)a * LD2 + c0] = make_float4(outv[0], outv[1], outv[2], outv[3]);
  }
  // fused rowsum (A2 entries are integers -> exact in any order)
  for (int off = 32; off > 0; off >>= 1) rsum += __shfl_down(rsum, off);
  if ((t & 63) == 0) wred[t >> 6] = rsum;
  __syncthreads();
  if (t == 0) dis2[a] = 1.0f / sqrtf(wred[0] + wred[1] + wred[2] + wred[3] + 2.0f);
}

// Row-sparse GCN aggregation + epilogue (+ optional fused score) — single wave,
// 2 features/thread, klist ascending via wave-synchronous ballot compaction, no barriers.
__global__ __launch_bounds__(64) void k_spmv(const float* __restrict__ A, int ncols, int ld,
                                             const float* __restrict__ Ysc,
                                             const float* __restrict__ dis,
                                             const float* __restrict__ bias,
                                             const float* __restrict__ p,
                                             float* __restrict__ H,
                                             float* __restrict__ score, int act) {
  __shared__ int klist[K1N];
  __shared__ float wlist[K1N];
  int r = blockIdx.x, t = threadIdx.x;
  const float* arow = A + (size_t)r * ld;
  unsigned long long below = (t == 0) ? 0ull : (~0ull >> (64 - t));
  int nnz = 0;
  for (int c0 = 0; c0 < ncols; c0 += 64) {
    int col = c0 + t;
    float w = (col < ncols) ? arow[col] : 0.0f;
    bool nz = (w != 0.0f);
    unsigned long long m = __ballot(nz);
    if (nz) {
      int pos = nnz + (int)__popcll(m & below);
      klist[pos] = col; wlist[pos] = w;
    }
    nnz += (int)__popcll(m);
  }
  int f = 2 * t;
  float ax = 0.0f, ay = 0.0f;
  int pp = 0;
  for (; pp + 4 <= nnz; pp += 4) {
    int k0 = klist[pp], k1 = klist[pp + 1], k2 = klist[pp + 2], k3 = klist[pp + 3];
    float w0 = wlist[pp], w1 = wlist[pp + 1], w2 = wlist[pp + 2], w3 = wlist[pp + 3];
    float2 y0 = *(const float2*)&Ysc[(size_t)k0 * HID + f];
    float2 y1 = *(const float2*)&Ysc[(size_t)k1 * HID + f];
    float2 y2 = *(const float2*)&Ysc[(size_t)k2 * HID + f];
    float2 y3 = *(const float2*)&Ysc[(size_t)k3 * HID + f];
    ax += w0 * y0.x; ay += w0 * y0.y;
    ax += w1 * y1.x; ay += w1 * y1.y;
    ax += w2 * y2.x; ay += w2 * y2.y;
    ax += w3 * y3.x; ay += w3 * y3.y;
  }
  for (; pp < nnz; ++pp) {
    float2 y = *(const float2*)&Ysc[(size_t)klist[pp] * HID + f];
    ax += wlist[pp] * y.x; ay += wlist[pp] * y.y;
  }
  float2 ys = *(const float2*)&Ysc[(size_t)r * HID + f];
  float dr = dis[r];
  float2 bv = *(const float2*)&bias[f];
  float z0 = dr * (ax + 2.0f * ys.x) + bv.x;
  float z1 = dr * (ay + 2.0f * ys.y) + bv.y;
  float h0v = act ? tanhf(z0) : z0;
  float h1v = act ? tanhf(z1) : z1;
  *(float2*)&H[(size_t)r * HID + f] = make_float2(h0v, h1v);
  if (p) {
    float2 pv = *(const float2*)&p[f];
    float sc = h0v * pv.x + h1v * pv.y;
    float pn = pv.x * pv.x + pv.y * pv.y;
    for (int off = 32; off > 0; off >>= 1) {
      sc += __shfl_down(sc, off);
      pn += __shfl_down(pn, off);
    }
    if (t == 0) score[r] = tanhf(sc * (1.0f / sqrtf(pn)));
  }
}

// Yfsc[i] = dis0[i] * ((h0[i] + scatter(u1b)) @ W_up1)   [N0 x 3]
__global__ void k_yf(const float* __restrict__ h0, const float* __restrict__ u1b,
                     const int* __restrict__ inv1, const float* __restrict__ Wup1,
                     const int* __restrict__ cnt_in, const int* __restrict__ selfc,
                     float* __restrict__ Yfsc) {
  __shared__ float red[3][HID];
  int i = blockIdx.x, t = threadIdx.x;
  float v = h0[i * HID + t];
  int ii = inv1[i];
  if (ii >= 0 && ii < K1N) v += u1b[ii * HID + t];
#pragma unroll
  for (int c = 0; c < 3; ++c) red[c][t] = v * Wup1[t * 3 + c];
  __syncthreads();
  for (int s = 64; s > 0; s >>= 1) {
    if (t < s) { red[0][t] += red[0][t + s]; red[1][t] += red[1][t + s]; red[2][t] += red[2][t + s]; }
    __syncthreads();
  }
  if (t < 3) {
    float d0 = 1.0f / sqrtf((float)(cnt_in[i] + selfc[i] + 2));
    Yfsc[i * 3 + t] = d0 * red[t][0];
  }
}

__global__ void k_final(const float* __restrict__ Yfsc, const int* __restrict__ cnt_in,
                        const int* __restrict__ col_in, const int* __restrict__ selfc,
                        const float* __restrict__ bup1, const float* __restrict__ z,
                        float* __restrict__ out) {
  int idx = blockIdx.x * blockDim.x + threadIdx.x;
  if (idx >= N0 * 3) return;
  int d = idx / 3, c = idx - d * 3;
  int cntu = cnt_in[d];
  int cnt = cntu > CAP ? CAP : cntu;
  float acc = (2.0f + (float)selfc[d]) * Yfsc[d * 3 + c];
  for (int e = 0; e < cnt; ++e) acc += Yfsc[col_in[d * CAP + e] * 3 + c];
  float d0 = 1.0f / sqrtf((float)(cntu + selfc[d] + 2));
  out[idx] = d0 * acc + bup1[c] + 0.1f * z[idx];
}

extern "C" void kernel_launch(void* const* d_in, const int* in_sizes, int n_in,
                              void* d_out, int out_size, void* d_ws, size_t ws_size,
                              hipStream_t stream) {
  const float* x   = (const float*)d_in[0];
  const float* z   = (const float*)d_in[1];
  const float* Wd0 = (const float*)d_in[2];
  const float* bd0 = (const float*)d_in[3];
  const float* Wd1 = (const float*)d_in[4];
  const float* bd1 = (const float*)d_in[5];
  const float* Wd2 = (const float*)d_in[6];
  const float* bd2 = (const float*)d_in[7];
  const float* p1  = (const float*)d_in[8];
  const float* p2  = (const float*)d_in[9];
  const float* Wu0 = (const float*)d_in[10];
  const float* bu0 = (const float*)d_in[11];
  const float* Wu1 = (const float*)d_in[12];
  const float* bu1 = (const float*)d_in[13];
  const int*   ei  = (const int*)d_in[14];

  if (ws_size < F_END * sizeof(float)) return;

  float* W     = (float*)d_ws;
  float* A1    = W + F_A1;
  float* Ac    = W + F_SCR;
  float* A2    = W + F_A2;
  float* Ysc   = W + F_YSC;
  float* h0    = W + F_H0;
  float* h1    = W + F_H1;
  float* h2    = W + F_H2;
  float* u1b   = W + F_U1B;
  float* Yfsc  = W + F_YF;
  float* score = W + F_SCORE;
  float* gate1 = W + F_GATE1;
  float* gate2 = W + F_GATE2;
  float* dis1  = W + F_DIS1;
  float* dis2  = W + F_DIS2;
  int* perm1   = (int*)(W + F_PERM1);
  int* perm2   = (int*)(W + F_PERM2);
  int* inv1    = (int*)(W + F_INV1);
  int* inv2    = (int*)(W + F_INV2);
  int* cnt_in  = (int*)(W + F_CNTI);
  int* cnt_out = (int*)(W + F_CNTO);
  int* selfc   = (int*)(W + F_SELF);
  int* col_in  = (int*)(W + F_CI);
  int* col_out = (int*)(W + F_CO);
  float* out   = (float*)d_out;

  // ---- init (single fused fill) ----
  k_init<<<1024, 256, 0, stream>>>(A1, gate1, perm1, inv1, cnt_in, out + N0 * 3);

  // ---- edge lists ----
  k_count<<<(E0 + 255) / 256, 256, 0, stream>>>(ei, cnt_in, cnt_out, selfc, col_in, col_out);

  // ---- level 0 GCN + pool-1 score ----
  k_yw2<<<(N0 + BM - 1) / BM, 256, 0, stream>>>(x, nullptr, nullptr, 32, N0, N0, Wd0,
                                                nullptr, nullptr, nullptr, cnt_in, selfc, Ysc);
  k_gcn_sparse<<<N0, 64, 0, stream>>>(Ysc, cnt_in, col_in, selfc, bd0, p1, h0, score);
  k_topk<<<1, 256, 0, stream>>>(score, N0, K1N, perm1, gate1, inv1);

  // ---- A1 = augment(A0)[perm1][:,perm1] ----
  k_pairs<<<N0, 128, 0, stream>>>(cnt_in, col_in, cnt_out, col_out, inv1, A1);
  k_rowsum<<<K1N, 256, 0, stream>>>(A1, K1N, LD1, dis1);

  // ---- level 1 GCN (sparse) + pool-2 score fused ----
  k_yw2<<<(K1N + BM - 1) / BM, 256, 0, stream>>>(h0, nullptr, nullptr, HID, N0, K1N, Wd1,
                                                 perm1, gate1, dis1, nullptr, nullptr, Ysc);
  k_spmv<<<K1N, 64, 0, stream>>>(A1, K1N, LD1, Ysc, dis1, bd1, p2, h1, score, 1);
  k_topk<<<1, 256, 0, stream>>>(score, K1N, K2N, perm2, gate2, inv2);

  // ---- A2 = augment(A1)[perm2][:,perm2] (+ fused dis2) ----
  k_cmp<<<K1N, 256, 0, stream>>>(A1, perm2, Ac);
  k_sq2<<<K2N, 256, 0, stream>>>(A1, Ac, perm2, A2, dis2);

  // ---- level 2 GCN (sparse) ----
  k_yw2<<<(K2N + BM - 1) / BM, 256, 0, stream>>>(h1, nullptr, nullptr, HID, K1N, K2N, Wd2,
                                                 perm2, gate2, dis2, nullptr, nullptr, Ysc);
  k_spmv<<<K2N, 64, 0, stream>>>(A2, K2N, LD2, Ysc, dis2, bd2, nullptr, h2, nullptr, 1);

  // ---- up path (combine fused into staging) ----
  k_yw2<<<(K1N + BM - 1) / BM, 256, 0, stream>>>(h1, h2, inv2, HID, K1N, K1N, Wu0,
                                                 nullptr, nullptr, dis1, nullptr, nullptr, Ysc);
  k_spmv<<<K1N, 64, 0, stream>>>(A1, K1N, LD1, Ysc, dis1, bu0, nullptr, u1b, nullptr, 1);

  // ---- final ----
  k_yf<<<N0, HID, 0, stream>>>(h0, u1b, inv1, Wu1, cnt_in, selfc, Yfsc);
  k_final<<<(N0 * 3 + 255) / 256, 256, 0, stream>>>(Yfsc, cnt_in, col_in, selfc, bu1, z, out);
}

// Round 10
// 300.343 us; speedup vs baseline: 1.0278x; 1.0278x over previous
//
#include <hip/hip_runtime.h>
#include <hip/hip_bf16.h>

#define N0   3000
#define E0   48000
#define K1N  1500
#define K2N  750
#define HID  128
#define CAP  128
#define LD1  1536  // padded leading dim for A1
#define LD2  768   // padded leading dim for A2/Ac
#define BM   32    // row-tile for k_yw2
#define ATS  36    // transposed X-tile stride (BM+4, bank-spread)

__device__ __forceinline__ unsigned fkey(float f) {
  unsigned u = __float_as_uint(f);
  return (u & 0x80000000u) ? ~u : (u | 0x80000000u);
}
__device__ __forceinline__ float inv_fkey(unsigned u) {
  unsigned v = (u & 0x80000000u) ? (u & 0x7FFFFFFFu) : ~u;
  return __uint_as_float(v);
}

// ---------------- workspace layout (float units) ----------------
constexpr size_t F_A1    = 0;                          // K1N*LD1
constexpr size_t F_SCR   = F_A1 + (size_t)K1N * LD1;   // Ac = K1N*LD2
constexpr size_t SCR_SZ  = 1155072;                    // >= K1N*LD2 (1,152,000)
constexpr size_t F_A2    = F_SCR + SCR_SZ;             // K2N*LD2
constexpr size_t F_YSC   = F_A2 + (size_t)K2N * LD2;   // N0*HID
constexpr size_t F_H0    = F_YSC + (size_t)N0 * HID;   // N0*HID
constexpr size_t F_H1    = F_H0 + (size_t)N0 * HID;    // K1N*HID
constexpr size_t F_H2    = F_H1 + (size_t)K1N * HID;   // K2N*HID
constexpr size_t F_U1    = F_H2 + (size_t)K2N * HID;   // (hole, kept for layout)
constexpr size_t F_U1B   = F_U1 + (size_t)K1N * HID;   // K1N*HID
constexpr size_t F_YF    = F_U1B + (size_t)K1N * HID;  // N0*3
constexpr size_t F_SCORE = F_YF + (size_t)N0 * 3;      // N0
constexpr size_t F_GATE1 = F_SCORE + N0;               // K1N  } contiguous zero fill
constexpr size_t F_GATE2 = F_GATE1 + K1N;              // K2N  }
constexpr size_t F_DIS0  = F_GATE2 + K2N;              // (unused)
constexpr size_t F_DIS1  = F_DIS0 + N0;                // K1N
constexpr size_t F_DIS2  = F_DIS1 + K1N;               // K2N
constexpr size_t F_PERM1 = F_DIS2 + K2N;               // K1N (int) } contiguous 0 fill
constexpr size_t F_PERM2 = F_PERM1 + K1N;              // K2N (int) }
constexpr size_t F_INV1  = F_PERM2 + K2N;              // N0  (int) } contiguous -1 fill
constexpr size_t F_INV2  = F_INV1 + N0;                // K1N (int) }
constexpr size_t F_CNTI  = F_INV2 + K1N;               // N0  (int) } contiguous 0 fill
constexpr size_t F_CNTO  = F_CNTI + N0;                // N0  (int) }
constexpr size_t F_SELF  = F_CNTO + N0;                // N0  (int) }
constexpr size_t F_CI    = F_SELF + N0;                // N0*CAP (int)
constexpr size_t F_CO    = F_CI + (size_t)N0 * CAP;    // N0*CAP (int)
constexpr size_t F_END   = F_CO + (size_t)N0 * CAP;

// ---------------- init: all fills fused (1 dispatch) ----------------
__global__ void k_init(float* __restrict__ A1, float* __restrict__ gate,
                       int* __restrict__ perm, int* __restrict__ inv,
                       int* __restrict__ cnt, float* __restrict__ outlab) {
  int i = blockIdx.x * blockDim.x + threadIdx.x, st = gridDim.x * blockDim.x;
  for (int j = i; j < K1N * LD1; j += st) A1[j] = 0.0f;
  for (int j = i; j < K1N + K2N; j += st) gate[j] = 0.0f;
  for (int j = i; j < K1N + K2N; j += st) perm[j] = 0;
  for (int j = i; j < N0 + K1N; j += st) inv[j] = -1;
  for (int j = i; j < 3 * N0; j += st) cnt[j] = 0;
  for (int j = i; j < N0 * 29; j += st) outlab[j] = 0.0f;
}

// Build per-node edge lists: col_in[d] = srcs of non-self in-edges, col_out[s] = dsts.
__global__ void k_count(const int* __restrict__ ei, int* cnt_in, int* cnt_out, int* selfc,
                        int* col_in, int* col_out) {
  int e = blockIdx.x * blockDim.x + threadIdx.x;
  if (e >= E0) return;
  int s = ei[e], d = ei[E0 + e];
  if (s == d) { atomicAdd(&selfc[d], 1); return; }
  int a = atomicAdd(&cnt_in[d], 1);
  if (a < CAP) col_in[d * CAP + a] = s;
  int b = atomicAdd(&cnt_out[s], 1);
  if (b < CAP) col_out[s * CAP + b] = d;
}

// Ysc[row][f] = scale(row) * sum_k Xeff[src(row)][k] * Wm[k][f]
// Xeff = X (+ X2[inv2c[row]] if combine). scale = (dis ? dis : 1/sqrt(cnt+self+2)) * gate.
__global__ __launch_bounds__(256) void k_yw2(const float* __restrict__ X,
                                             const float* __restrict__ X2,
                                             const int* __restrict__ inv2c,
                                             int Kin, int nsrc, int n,
                                             const float* __restrict__ Wm,
                                             const int* __restrict__ perm,
                                             const float* __restrict__ gate,
                                             const float* __restrict__ dis,
                                             const int* __restrict__ cntd,
                                             const int* __restrict__ selfd,
                                             float* __restrict__ Ysc) {
  __shared__ float Wt[32 * HID];   // 16 KB, [kk][f]
  __shared__ float Xt[32 * ATS];   // 4.6 KB, [kk][row] transposed
  int t = threadIdx.x;
  int r0 = blockIdx.x * BM;
  int f4 = (t & 31) * 4;
  int rg = t >> 5;                 // 0..7 -> rows r0 + rg*4 + {0..3}
  float4 acc0 = {0,0,0,0}, acc1 = {0,0,0,0}, acc2 = {0,0,0,0}, acc3 = {0,0,0,0};
  for (int kb = 0; kb < Kin; kb += 32) {
    {
      const float4* src = (const float4*)(Wm + (size_t)kb * HID);
      float4* dst = (float4*)Wt;
#pragma unroll
      for (int i = 0; i < 4; ++i) dst[i * 256 + t] = src[i * 256 + t];
    }
    {
      int j = t >> 3;
      int k4 = (t & 7) * 4;
      int r = r0 + j;
      int src_row = (r < n) ? r : (n - 1);
      if (perm) {
        int s = perm[src_row];
        if (s < 0) s = 0;
        if (s >= nsrc) s = nsrc - 1;
        src_row = s;
      }
      float4 xv = *(const float4*)(X + (size_t)src_row * Kin + kb + k4);
      if (X2) {
        int ii = inv2c[src_row];
        if (ii >= 0 && ii < K2N) {
          float4 x2 = *(const float4*)(X2 + (size_t)ii * Kin + kb + k4);
          xv.x += x2.x; xv.y += x2.y; xv.z += x2.z; xv.w += x2.w;
        }
      }
      Xt[(k4 + 0) * ATS + j] = xv.x;
      Xt[(k4 + 1) * ATS + j] = xv.y;
      Xt[(k4 + 2) * ATS + j] = xv.z;
      Xt[(k4 + 3) * ATS + j] = xv.w;
    }
    __syncthreads();
#pragma unroll 4
    for (int kk = 0; kk < 32; ++kk) {
      float4 y = *(const float4*)&Wt[kk * HID + f4];
      float4 a = *(const float4*)&Xt[kk * ATS + rg * 4];
      acc0.x += a.x * y.x; acc0.y += a.x * y.y; acc0.z += a.x * y.z; acc0.w += a.x * y.w;
      acc1.x += a.y * y.x; acc1.y += a.y * y.y; acc1.z += a.y * y.z; acc1.w += a.y * y.w;
      acc2.x += a.z * y.x; acc2.y += a.z * y.y; acc2.z += a.z * y.z; acc2.w += a.z * y.w;
      acc3.x += a.w * y.x; acc3.y += a.w * y.y; acc3.z += a.w * y.z; acc3.w += a.w * y.w;
    }
    __syncthreads();
  }
  int r = r0 + rg * 4;
  float4* accs[4] = {&acc0, &acc1, &acc2, &acc3};
#pragma unroll
  for (int j = 0; j < 4; ++j) {
    int row = r + j;
    if (row >= n) continue;
    float g = gate ? gate[row] : 1.0f;
    float d = dis ? dis[row] : (1.0f / sqrtf((float)(cntd[row] + selfd[row] + 2)));
    float s = d * g;
    float4 a = *accs[j];
    *(float4*)&Ysc[(size_t)row * HID + f4] = make_float4(s * a.x, s * a.y, s * a.z, s * a.w);
  }
}

// Level-0 sparse GCN + fused score (128 threads = 2 waves; round-8 verified version)
__global__ void k_gcn_sparse(const float* __restrict__ Ysc, const int* __restrict__ cnt_in,
                             const int* __restrict__ col_in, const int* __restrict__ selfc,
                             const float* __restrict__ bias, const float* __restrict__ p,
                             float* __restrict__ H, float* __restrict__ score) {
  __shared__ float red[HID];
  __shared__ float red2[HID];
  int d = blockIdx.x, f = threadIdx.x;
  int cntu = cnt_in[d];
  int cnt = cntu > CAP ? CAP : cntu;
  float acc = (2.0f + (float)selfc[d]) * Ysc[d * HID + f];
  for (int e = 0; e < cnt; ++e) acc += Ysc[col_in[d * CAP + e] * HID + f];
  float d0 = 1.0f / sqrtf((float)(cntu + selfc[d] + 2));
  float h = tanhf(d0 * acc + bias[f]);
  H[d * HID + f] = h;
  float pv = p[f];
  red[f] = h * pv;
  red2[f] = pv * pv;
  __syncthreads();
  for (int s = 64; s > 0; s >>= 1) {
    if (f < s) { red[f] += red[f + s]; red2[f] += red2[f + s]; }
    __syncthreads();
  }
  if (f == 0) score[d] = tanhf(red[0] * (1.0f / sqrtf(red2[0])));
}

// Top-K, one 256-thread block. Radix-select with hierarchical set compaction
// between passes; final index-ordered ballot compaction (verified) over score[].
__global__ __launch_bounds__(256) void k_topk(const float* __restrict__ score, int n, int K,
                                              int* __restrict__ perm, float* __restrict__ gatec,
                                              int* __restrict__ inv) {
  __shared__ unsigned setA[N0];
  __shared__ unsigned setB[N0];
  __shared__ int hist[256];
  __shared__ int sscan[257];
  __shared__ unsigned pfx_sh;
  __shared__ int rem_sh;
  __shared__ int cnt_sh;
  int t = threadIdx.x;
  for (int i = t; i < n; i += 256) setA[i] = fkey(score[i]);
  __syncthreads();

  unsigned prefix = 0; int rem = K; int m = n;
  unsigned* cur = setA; unsigned* nxt = setB;
  for (int pass = 3; pass >= 0; --pass) {
    hist[t] = 0;
    __syncthreads();
    for (int i = t; i < m; i += 256) atomicAdd(&hist[(cur[i] >> (pass * 8)) & 255], 1);
    __syncthreads();
    sscan[t] = hist[t];
    if (t == 0) sscan[256] = 0;
    __syncthreads();
    for (int off = 1; off < 256; off <<= 1) {
      int add = (t + off < 256) ? sscan[t + off] : 0;
      __syncthreads();
      sscan[t] += add;
      __syncthreads();
    }
    if (sscan[t] >= rem && sscan[t + 1] < rem) {
      pfx_sh = prefix | ((unsigned)t << (pass * 8));
      rem_sh = rem - sscan[t + 1];
    }
    __syncthreads();
    prefix = pfx_sh; rem = rem_sh;
    if (pass > 0) {
      unsigned dg = (prefix >> (pass * 8)) & 255u;
      if (t == 0) cnt_sh = 0;
      __syncthreads();
      int lane = t & 63;
      unsigned long long below = (lane == 0) ? 0ull : (~0ull >> (64 - lane));
      for (int c0 = 0; c0 < m; c0 += 256) {
        int i = c0 + t;
        unsigned u = (i < m) ? cur[i] : 0u;
        bool match = (i < m) && (((u >> (pass * 8)) & 255u) == dg);
        unsigned long long mm = __ballot(match);
        int cw = (int)__popcll(mm);
        int basew = 0;
        if (lane == 0 && cw) basew = atomicAdd(&cnt_sh, cw);
        basew = __shfl(basew, 0);
        if (match) nxt[basew + (int)__popcll(mm & below)] = u;
      }
      __syncthreads();
      m = cnt_sh;
      unsigned* tmp = cur; cur = nxt; nxt = tmp;
    }
  }
  unsigned uthr = prefix;
  int c_gt = K - rem;
  if (t >= 64) return;
  int lane = t;
  unsigned long long below = (lane == 0) ? 0ull : (~0ull >> (64 - lane));
  int base_gt = 0, base_eq = 0;
  for (int chunk = 0; chunk < n; chunk += 64) {
    int i = chunk + lane;
    bool valid = (i < n);
    unsigned u = valid ? fkey(score[i]) : 0u;
    bool isgt = valid && (u > uthr);
    bool iseq = valid && (u == uthr);
    unsigned long long mg = __ballot(isgt);
    unsigned long long me = __ballot(iseq);
    if (isgt) {
      int pos = base_gt + (int)__popcll(mg & below);
      perm[pos] = i; gatec[pos] = inv_fkey(u); inv[i] = pos;
    } else if (iseq) {
      int er = base_eq + (int)__popcll(me & below);
      if (er < rem) { int pos = c_gt + er; perm[pos] = i; gatec[pos] = inv_fkey(u); inv[i] = pos; }
    }
    base_gt += (int)__popcll(mg);
    base_eq += (int)__popcll(me);
  }
}

// A0 augment restricted to selected nodes, fused with the +2*A' term.
__global__ void k_pairs(const int* __restrict__ cnt_in, const int* __restrict__ col_in,
                        const int* __restrict__ cnt_out, const int* __restrict__ col_out,
                        const int* __restrict__ inv, float* __restrict__ A1) {
  __shared__ int outl[CAP], inl[CAP], invo[CAP], invi[CAP];
  int k = blockIdx.x, t = threadIdx.x;
  int no = cnt_out[k]; if (no > CAP) no = CAP;
  int ni = cnt_in[k];  if (ni > CAP) ni = CAP;
  if (t < no) { int i = col_out[k * CAP + t]; outl[t] = i; invo[t] = inv[i]; }
  if (t < ni) { int j = col_in[k * CAP + t];  inl[t] = j;  invi[t] = inv[j]; }
  __syncthreads();
  int invk = inv[k];
  if (t < ni && invk >= 0) {
    int jj = invi[t];
    if (jj >= 0) atomicAdd(&A1[(size_t)invk * LD1 + jj], 2.0f);   // edge term (2*A')
  }
  for (int a = t; a < no; a += blockDim.x) {
    int i = outl[a], ii = invo[a];
    if (ii < 0) continue;
    for (int b = 0; b < ni; ++b) {
      int jj = invi[b];
      if (jj >= 0 && i != inl[b]) atomicAdd(&A1[(size_t)ii * LD1 + jj], 1.0f);
    }
  }
}

__global__ void k_rowsum(const float* __restrict__ A, int n, int ld, float* __restrict__ dis) {
  __shared__ float red[256];
  int r = blockIdx.x, t = threadIdx.x;
  float acc = 0.0f;
  for (int c = t; c < n; c += 256) acc += A[(size_t)r * ld + c];
  red[t] = acc; __syncthreads();
  for (int s = 128; s > 0; s >>= 1) { if (t < s) red[t] += red[t + s]; __syncthreads(); }
  if (t == 0) dis[r] = 1.0f / sqrtf(red[0] + 2.0f);
}

// Column compaction: Ac[k][b] = A1[k][perm2[b]]  (b < K2N, else 0); grid = K1N rows
__global__ __launch_bounds__(256) void k_cmp(const float* __restrict__ A1,
                                             const int* __restrict__ perm2,
                                             float* __restrict__ Ac) {
  __shared__ int q[K2N];
  int k = blockIdx.x, t = threadIdx.x;
  for (int i = t; i < K2N; i += 256) {
    int v = perm2[i];
    if (v < 0) v = 0;
    if (v >= K1N) v = K1N - 1;
    q[i] = v;
  }
  __syncthreads();
  const float* row = A1 + (size_t)k * LD1;
  float* dst = Ac + (size_t)k * LD2;
  for (int b = t; b < LD2; b += 256) dst[b] = (b < K2N) ? row[q[b]] : 0.0f;
}

// A2[a][b] = (b!=a) ? sum_k A1[qa][k]*Ac[k][b] + 2*A1[qa][perm2[b]] : 0
// + fused dis2[a] = 1/sqrt(rowsum(A2[a]) + 2)  (integer-exact)
__global__ __launch_bounds__(256) void k_sq2(const float* __restrict__ A1,
                                             const float* __restrict__ Ac,
                                             const int* __restrict__ perm2,
                                             float* __restrict__ A2,
                                             float* __restrict__ dis2) {
  __shared__ int klist[K1N];
  __shared__ float wlist[K1N];
  __shared__ int nnz_sh;
  __shared__ float wred[4];
  int a = blockIdx.x, t = threadIdx.x;
  int qa = perm2[a];
  if (qa < 0) qa = 0;
  if (qa >= K1N) qa = K1N - 1;
  if (t == 0) nnz_sh = 0;
  __syncthreads();
  const float* arow = A1 + (size_t)qa * LD1;
  for (int c = t; c < K1N; c += 256) {
    float w = arow[c];
    if (w != 0.0f) { int p = atomicAdd(&nnz_sh, 1); klist[p] = c; wlist[p] = w; }
  }
  __syncthreads();
  int nnz = nnz_sh;
  int c0 = t * 4;
  bool active = (c0 < LD2);
  float4 acc = make_float4(0.f, 0.f, 0.f, 0.f);
  int p = 0;
  for (; p + 4 <= nnz; p += 4) {
    int k0 = klist[p], k1 = klist[p + 1], k2 = klist[p + 2], k3 = klist[p + 3];
    float w0 = wlist[p], w1 = wlist[p + 1], w2 = wlist[p + 2], w3 = wlist[p + 3];
    if (active) {
      float4 v0 = *(const float4*)&Ac[(size_t)k0 * LD2 + c0];
      float4 v1 = *(const float4*)&Ac[(size_t)k1 * LD2 + c0];
      float4 v2 = *(const float4*)&Ac[(size_t)k2 * LD2 + c0];
      float4 v3 = *(const float4*)&Ac[(size_t)k3 * LD2 + c0];
      acc.x += w0 * v0.x; acc.y += w0 * v0.y; acc.z += w0 * v0.z; acc.w += w0 * v0.w;
      acc.x += w1 * v1.x; acc.y += w1 * v1.y; acc.z += w1 * v1.z; acc.w += w1 * v1.w;
      acc.x += w2 * v2.x; acc.y += w2 * v2.y; acc.z += w2 * v2.z; acc.w += w2 * v2.w;
      acc.x += w3 * v3.x; acc.y += w3 * v3.y; acc.z += w3 * v3.z; acc.w += w3 * v3.w;
    }
  }
  for (; p < nnz; ++p) {
    int k = klist[p]; float w = wlist[p];
    if (active) {
      float4 v = *(const float4*)&Ac[(size_t)k * LD2 + c0];
      acc.x += w * v.x; acc.y += w * v.y; acc.z += w * v.z; acc.w += w * v.w;
    }
  }
  float rsum = 0.0f;
  if (active) {
    float accv[4] = {acc.x, acc.y, acc.z, acc.w};
    float outv[4];
#pragma unroll
    for (int j = 0; j < 4; ++j) {
      int col = c0 + j;
      float v = 0.0f;
      if (col < K2N && col != a) {
        int qb = perm2[col];
        if (qb < 0) qb = 0;
        if (qb >= K1N) qb = K1N - 1;
        v = accv[j] + 2.0f * arow[qb];
      }
      outv[j] = v;
      rsum += v;
    }
    *(float4*)&A2[(size_t)a * LD2 + c0] = make_float4(outv[0], outv[1], outv[2], outv[3]);
  }
  for (int off = 32; off > 0; off >>= 1) rsum += __shfl_down(rsum, off);
  if ((t & 63) == 0) wred[t >> 6] = rsum;
  __syncthreads();
  if (t == 0) dis2[a] = 1.0f / sqrtf(wred[0] + wred[1] + wred[2] + wred[3] + 2.0f);
}

// Row-sparse GCN aggregation + epilogue (+ optional fused score) — 128 threads
// (2 waves; round-8 verified version). klist ascending via per-chunk ballot compaction.
__global__ __launch_bounds__(128) void k_spmv(const float* __restrict__ A, int ncols, int ld,
                                              const float* __restrict__ Ysc,
                                              const float* __restrict__ dis,
                                              const float* __restrict__ bias,
                                              const float* __restrict__ p,
                                              float* __restrict__ H,
                                              float* __restrict__ score, int act) {
  __shared__ int klist[K1N];
  __shared__ float wlist[K1N];
  __shared__ int cntw[2];
  __shared__ float red[HID];
  __shared__ float red2[HID];
  int r = blockIdx.x, t = threadIdx.x;
  const float* arow = A + (size_t)r * ld;
  int wid = t >> 6, lane = t & 63;
  unsigned long long below = (lane == 0) ? 0ull : (~0ull >> (64 - lane));
  int base = 0;
  for (int c0 = 0; c0 < ncols; c0 += 128) {
    int col = c0 + t;
    float w = (col < ncols) ? arow[col] : 0.0f;
    bool nz = (w != 0.0f);
    unsigned long long m = __ballot(nz);
    if (lane == 0) cntw[wid] = (int)__popcll(m);
    __syncthreads();
    int pos = base + (wid ? cntw[0] : 0) + (int)__popcll(m & below);
    if (nz) { klist[pos] = col; wlist[pos] = w; }
    base += cntw[0] + cntw[1];
    __syncthreads();
  }
  int nnz = base;
  float acc = 0.0f;
  int pp = 0;
  for (; pp + 4 <= nnz; pp += 4) {
    float y0 = Ysc[(size_t)klist[pp + 0] * HID + t];
    float y1 = Ysc[(size_t)klist[pp + 1] * HID + t];
    float y2 = Ysc[(size_t)klist[pp + 2] * HID + t];
    float y3 = Ysc[(size_t)klist[pp + 3] * HID + t];
    acc += wlist[pp + 0] * y0;
    acc += wlist[pp + 1] * y1;
    acc += wlist[pp + 2] * y2;
    acc += wlist[pp + 3] * y3;
  }
  for (; pp < nnz; ++pp) acc += wlist[pp] * Ysc[(size_t)klist[pp] * HID + t];
  float zv = dis[r] * (acc + 2.0f * Ysc[(size_t)r * HID + t]) + bias[t];
  float h = act ? tanhf(zv) : zv;
  H[(size_t)r * HID + t] = h;
  if (p) {
    float pv = p[t];
    red[t] = h * pv;
    red2[t] = pv * pv;
    __syncthreads();
    for (int s = 64; s > 0; s >>= 1) {
      if (t < s) { red[t] += red[t + s]; red2[t] += red2[t + s]; }
      __syncthreads();
    }
    if (t == 0) score[r] = tanhf(red[0] * (1.0f / sqrtf(red2[0])));
  }
}

// Yfsc[i] = dis0[i] * ((h0[i] + scatter(u1b)) @ W_up1)   [N0 x 3]
__global__ void k_yf(const float* __restrict__ h0, const float* __restrict__ u1b,
                     const int* __restrict__ inv1, const float* __restrict__ Wup1,
                     const int* __restrict__ cnt_in, const int* __restrict__ selfc,
                     float* __restrict__ Yfsc) {
  __shared__ float red[3][HID];
  int i = blockIdx.x, t = threadIdx.x;
  float v = h0[i * HID + t];
  int ii = inv1[i];
  if (ii >= 0 && ii < K1N) v += u1b[ii * HID + t];
#pragma unroll
  for (int c = 0; c < 3; ++c) red[c][t] = v * Wup1[t * 3 + c];
  __syncthreads();
  for (int s = 64; s > 0; s >>= 1) {
    if (t < s) { red[0][t] += red[0][t + s]; red[1][t] += red[1][t + s]; red[2][t] += red[2][t + s]; }
    __syncthreads();
  }
  if (t < 3) {
    float d0 = 1.0f / sqrtf((float)(cnt_in[i] + selfc[i] + 2));
    Yfsc[i * 3 + t] = d0 * red[t][0];
  }
}

__global__ void k_final(const float* __restrict__ Yfsc, const int* __restrict__ cnt_in,
                        const int* __restrict__ col_in, const int* __restrict__ selfc,
                        const float* __restrict__ bup1, const float* __restrict__ z,
                        float* __restrict__ out) {
  int idx = blockIdx.x * blockDim.x + threadIdx.x;
  if (idx >= N0 * 3) return;
  int d = idx / 3, c = idx - d * 3;
  int cntu = cnt_in[d];
  int cnt = cntu > CAP ? CAP : cntu;
  float acc = (2.0f + (float)selfc[d]) * Yfsc[d * 3 + c];
  for (int e = 0; e < cnt; ++e) acc += Yfsc[col_in[d * CAP + e] * 3 + c];
  float d0 = 1.0f / sqrtf((float)(cntu + selfc[d] + 2));
  out[idx] = d0 * acc + bup1[c] + 0.1f * z[idx];
}

extern "C" void kernel_launch(void* const* d_in, const int* in_sizes, int n_in,
                              void* d_out, int out_size, void* d_ws, size_t ws_size,
                              hipStream_t stream) {
  const float* x   = (const float*)d_in[0];
  const float* z   = (const float*)d_in[1];
  const float* Wd0 = (const float*)d_in[2];
  const float* bd0 = (const float*)d_in[3];
  const float* Wd1 = (const float*)d_in[4];
  const float* bd1 = (const float*)d_in[5];
  const float* Wd2 = (const float*)d_in[6];
  const float* bd2 = (const float*)d_in[7];
  const float* p1  = (const float*)d_in[8];
  const float* p2  = (const float*)d_in[9];
  const float* Wu0 = (const float*)d_in[10];
  const float* bu0 = (const float*)d_in[11];
  const float* Wu1 = (const float*)d_in[12];
  const float* bu1 = (const float*)d_in[13];
  const int*   ei  = (const int*)d_in[14];

  if (ws_size < F_END * sizeof(float)) return;

  float* W     = (float*)d_ws;
  float* A1    = W + F_A1;
  float* Ac    = W + F_SCR;
  float* A2    = W + F_A2;
  float* Ysc   = W + F_YSC;
  float* h0    = W + F_H0;
  float* h1    = W + F_H1;
  float* h2    = W + F_H2;
  float* u1b   = W + F_U1B;
  float* Yfsc  = W + F_YF;
  float* score = W + F_SCORE;
  float* gate1 = W + F_GATE1;
  float* gate2 = W + F_GATE2;
  float* dis1  = W + F_DIS1;
  float* dis2  = W + F_DIS2;
  int* perm1   = (int*)(W + F_PERM1);
  int* perm2   = (int*)(W + F_PERM2);
  int* inv1    = (int*)(W + F_INV1);
  int* inv2    = (int*)(W + F_INV2);
  int* cnt_in  = (int*)(W + F_CNTI);
  int* cnt_out = (int*)(W + F_CNTO);
  int* selfc   = (int*)(W + F_SELF);
  int* col_in  = (int*)(W + F_CI);
  int* col_out = (int*)(W + F_CO);
  float* out   = (float*)d_out;

  // ---- init (single fused fill) ----
  k_init<<<1024, 256, 0, stream>>>(A1, gate1, perm1, inv1, cnt_in, out + N0 * 3);

  // ---- edge lists ----
  k_count<<<(E0 + 255) / 256, 256, 0, stream>>>(ei, cnt_in, cnt_out, selfc, col_in, col_out);

  // ---- level 0 GCN + pool-1 score ----
  k_yw2<<<(N0 + BM - 1) / BM, 256, 0, stream>>>(x, nullptr, nullptr, 32, N0, N0, Wd0,
                                                nullptr, nullptr, nullptr, cnt_in, selfc, Ysc);
  k_gcn_sparse<<<N0, HID, 0, stream>>>(Ysc, cnt_in, col_in, selfc, bd0, p1, h0, score);
  k_topk<<<1, 256, 0, stream>>>(score, N0, K1N, perm1, gate1, inv1);

  // ---- A1 = augment(A0)[perm1][:,perm1] ----
  k_pairs<<<N0, 128, 0, stream>>>(cnt_in, col_in, cnt_out, col_out, inv1, A1);
  k_rowsum<<<K1N, 256, 0, stream>>>(A1, K1N, LD1, dis1);

  // ---- level 1 GCN (sparse) + pool-2 score fused ----
  k_yw2<<<(K1N + BM - 1) / BM, 256, 0, stream>>>(h0, nullptr, nullptr, HID, N0, K1N, Wd1,
                                                 perm1, gate1, dis1, nullptr, nullptr, Ysc);
  k_spmv<<<K1N, 128, 0, stream>>>(A1, K1N, LD1, Ysc, dis1, bd1, p2, h1, score, 1);
  k_topk<<<1, 256, 0, stream>>>(score, K1N, K2N, perm2, gate2, inv2);

  // ---- A2 = augment(A1)[perm2][:,perm2] (+ fused dis2) ----
  k_cmp<<<K1N, 256, 0, stream>>>(A1, perm2, Ac);
  k_sq2<<<K2N, 256, 0, stream>>>(A1, Ac, perm2, A2, dis2);

  // ---- level 2 GCN (sparse) ----
  k_yw2<<<(K2N + BM - 1) / BM, 256, 0, stream>>>(h1, nullptr, nullptr, HID, K1N, K2N, Wd2,
                                                 perm2, gate2, dis2, nullptr, nullptr, Ysc);
  k_spmv<<<K2N, 128, 0, stream>>>(A2, K2N, LD2, Ysc, dis2, bd2, nullptr, h2, nullptr, 1);

  // ---- up path (combine fused into staging) ----
  k_yw2<<<(K1N + BM - 1) / BM, 256, 0, stream>>>(h1, h2, inv2, HID, K1N, K1N, Wu0,
                                                 nullptr, nullptr, dis1, nullptr, nullptr, Ysc);
  k_spmv<<<K1N, 128, 0, stream>>>(A1, K1N, LD1, Ysc, dis1, bu0, nullptr, u1b, nullptr, 1);

  // ---- final ----
  k_yf<<<N0, HID, 0, stream>>>(h0, u1b, inv1, Wu1, cnt_in, selfc, Yfsc);
  k_final<<<(N0 * 3 + 255) / 256, 256, 0, stream>>>(Yfsc, cnt_in, col_in, selfc, bu1, z, out);
}

// Round 11
// 298.284 us; speedup vs baseline: 1.0349x; 1.0069x over previous
//
#include <hip/hip_runtime.h>
#include <hip/hip_bf16.h>

#define N0   3000
#define E0   48000
#define K1N  1500
#define K2N  750
#define HID  128
#define CAP  128
#define LD1  1536  // padded leading dim for A1
#define LD2  768   // padded leading dim for A2/Ac
#define BM   32    // row-tile for k_yw2
#define ATS  36    // transposed X-tile stride (BM+4, bank-spread)

__device__ __forceinline__ unsigned fkey(float f) {
  unsigned u = __float_as_uint(f);
  return (u & 0x80000000u) ? ~u : (u | 0x80000000u);
}
__device__ __forceinline__ float inv_fkey(unsigned u) {
  unsigned v = (u & 0x80000000u) ? (u & 0x7FFFFFFFu) : ~u;
  return __uint_as_float(v);
}

// ---------------- workspace layout (float units) ----------------
constexpr size_t F_A1    = 0;                          // K1N*LD1
constexpr size_t F_SCR   = F_A1 + (size_t)K1N * LD1;   // Ac (int16) = K1N*LD2 shorts
constexpr size_t SCR_SZ  = 1155072;                    // plenty
constexpr size_t F_A2    = F_SCR + SCR_SZ;             // K2N*LD2
constexpr size_t F_YSC   = F_A2 + (size_t)K2N * LD2;   // N0*HID
constexpr size_t F_H0    = F_YSC + (size_t)N0 * HID;   // N0*HID
constexpr size_t F_H1    = F_H0 + (size_t)N0 * HID;    // K1N*HID
constexpr size_t F_H2    = F_H1 + (size_t)K1N * HID;   // K2N*HID
constexpr size_t F_U1    = F_H2 + (size_t)K2N * HID;   // (hole, kept for layout)
constexpr size_t F_U1B   = F_U1 + (size_t)K1N * HID;   // K1N*HID
constexpr size_t F_YF    = F_U1B + (size_t)K1N * HID;  // N0*3
constexpr size_t F_SCORE = F_YF + (size_t)N0 * 3;      // N0
constexpr size_t F_GATE1 = F_SCORE + N0;               // K1N  } contiguous zero fill
constexpr size_t F_GATE2 = F_GATE1 + K1N;              // K2N  }
constexpr size_t F_DIS0  = F_GATE2 + K2N;              // (unused)
constexpr size_t F_DIS1  = F_DIS0 + N0;                // K1N
constexpr size_t F_DIS2  = F_DIS1 + K1N;               // K2N
constexpr size_t F_PERM1 = F_DIS2 + K2N;               // K1N (int) } contiguous 0 fill
constexpr size_t F_PERM2 = F_PERM1 + K1N;              // K2N (int) }
constexpr size_t F_INV1  = F_PERM2 + K2N;              // N0  (int) } contiguous -1 fill
constexpr size_t F_INV2  = F_INV1 + N0;                // K1N (int) }
constexpr size_t F_CNTI  = F_INV2 + K1N;               // N0  (int) } contiguous 0 fill
constexpr size_t F_CNTO  = F_CNTI + N0;                // N0  (int) }
constexpr size_t F_SELF  = F_CNTO + N0;                // N0  (int) }
constexpr size_t F_CI    = F_SELF + N0;                // N0*CAP (int)
constexpr size_t F_CO    = F_CI + (size_t)N0 * CAP;    // N0*CAP (int)
constexpr size_t F_END   = F_CO + (size_t)N0 * CAP;

// ---------------- init: all fills fused (1 dispatch) ----------------
__global__ void k_init(float* __restrict__ A1, float* __restrict__ gate,
                       int* __restrict__ perm, int* __restrict__ inv,
                       int* __restrict__ cnt, float* __restrict__ outlab) {
  int i = blockIdx.x * blockDim.x + threadIdx.x, st = gridDim.x * blockDim.x;
  for (int j = i; j < K1N * LD1; j += st) A1[j] = 0.0f;
  for (int j = i; j < K1N + K2N; j += st) gate[j] = 0.0f;
  for (int j = i; j < K1N + K2N; j += st) perm[j] = 0;
  for (int j = i; j < N0 + K1N; j += st) inv[j] = -1;
  for (int j = i; j < 3 * N0; j += st) cnt[j] = 0;
  for (int j = i; j < N0 * 29; j += st) outlab[j] = 0.0f;
}

// Build per-node edge lists: col_in[d] = srcs of non-self in-edges, col_out[s] = dsts.
__global__ void k_count(const int* __restrict__ ei, int* cnt_in, int* cnt_out, int* selfc,
                        int* col_in, int* col_out) {
  int e = blockIdx.x * blockDim.x + threadIdx.x;
  if (e >= E0) return;
  int s = ei[e], d = ei[E0 + e];
  if (s == d) { atomicAdd(&selfc[d], 1); return; }
  int a = atomicAdd(&cnt_in[d], 1);
  if (a < CAP) col_in[d * CAP + a] = s;
  int b = atomicAdd(&cnt_out[s], 1);
  if (b < CAP) col_out[s * CAP + b] = d;
}

// Ysc[row][f] = scale(row) * sum_k Xeff[src(row)][k] * Wm[k][f]
__global__ __launch_bounds__(256) void k_yw2(const float* __restrict__ X,
                                             const float* __restrict__ X2,
                                             const int* __restrict__ inv2c,
                                             int Kin, int nsrc, int n,
                                             const float* __restrict__ Wm,
                                             const int* __restrict__ perm,
                                             const float* __restrict__ gate,
                                             const float* __restrict__ dis,
                                             const int* __restrict__ cntd,
                                             const int* __restrict__ selfd,
                                             float* __restrict__ Ysc) {
  __shared__ float Wt[32 * HID];   // 16 KB, [kk][f]
  __shared__ float Xt[32 * ATS];   // 4.6 KB, [kk][row] transposed
  int t = threadIdx.x;
  int r0 = blockIdx.x * BM;
  int f4 = (t & 31) * 4;
  int rg = t >> 5;                 // 0..7 -> rows r0 + rg*4 + {0..3}
  float4 acc0 = {0,0,0,0}, acc1 = {0,0,0,0}, acc2 = {0,0,0,0}, acc3 = {0,0,0,0};
  for (int kb = 0; kb < Kin; kb += 32) {
    {
      const float4* src = (const float4*)(Wm + (size_t)kb * HID);
      float4* dst = (float4*)Wt;
#pragma unroll
      for (int i = 0; i < 4; ++i) dst[i * 256 + t] = src[i * 256 + t];
    }
    {
      int j = t >> 3;
      int k4 = (t & 7) * 4;
      int r = r0 + j;
      int src_row = (r < n) ? r : (n - 1);
      if (perm) {
        int s = perm[src_row];
        if (s < 0) s = 0;
        if (s >= nsrc) s = nsrc - 1;
        src_row = s;
      }
      float4 xv = *(const float4*)(X + (size_t)src_row * Kin + kb + k4);
      if (X2) {
        int ii = inv2c[src_row];
        if (ii >= 0 && ii < K2N) {
          float4 x2 = *(const float4*)(X2 + (size_t)ii * Kin + kb + k4);
          xv.x += x2.x; xv.y += x2.y; xv.z += x2.z; xv.w += x2.w;
        }
      }
      Xt[(k4 + 0) * ATS + j] = xv.x;
      Xt[(k4 + 1) * ATS + j] = xv.y;
      Xt[(k4 + 2) * ATS + j] = xv.z;
      Xt[(k4 + 3) * ATS + j] = xv.w;
    }
    __syncthreads();
#pragma unroll 4
    for (int kk = 0; kk < 32; ++kk) {
      float4 y = *(const float4*)&Wt[kk * HID + f4];
      float4 a = *(const float4*)&Xt[kk * ATS + rg * 4];
      acc0.x += a.x * y.x; acc0.y += a.x * y.y; acc0.z += a.x * y.z; acc0.w += a.x * y.w;
      acc1.x += a.y * y.x; acc1.y += a.y * y.y; acc1.z += a.y * y.z; acc1.w += a.y * y.w;
      acc2.x += a.z * y.x; acc2.y += a.z * y.y; acc2.z += a.z * y.z; acc2.w += a.z * y.w;
      acc3.x += a.w * y.x; acc3.y += a.w * y.y; acc3.z += a.w * y.z; acc3.w += a.w * y.w;
    }
    __syncthreads();
  }
  int r = r0 + rg * 4;
  float4* accs[4] = {&acc0, &acc1, &acc2, &acc3};
#pragma unroll
  for (int j = 0; j < 4; ++j) {
    int row = r + j;
    if (row >= n) continue;
    float g = gate ? gate[row] : 1.0f;
    float d = dis ? dis[row] : (1.0f / sqrtf((float)(cntd[row] + selfd[row] + 2)));
    float s = d * g;
    float4 a = *accs[j];
    *(float4*)&Ysc[(size_t)row * HID + f4] = make_float4(s * a.x, s * a.y, s * a.z, s * a.w);
  }
}

// Level-0 sparse GCN + fused score (128 threads = 2 waves)
__global__ void k_gcn_sparse(const float* __restrict__ Ysc, const int* __restrict__ cnt_in,
                             const int* __restrict__ col_in, const int* __restrict__ selfc,
                             const float* __restrict__ bias, const float* __restrict__ p,
                             float* __restrict__ H, float* __restrict__ score) {
  __shared__ float red[HID];
  __shared__ float red2[HID];
  int d = blockIdx.x, f = threadIdx.x;
  int cntu = cnt_in[d];
  int cnt = cntu > CAP ? CAP : cntu;
  float acc = (2.0f + (float)selfc[d]) * Ysc[d * HID + f];
  for (int e = 0; e < cnt; ++e) acc += Ysc[col_in[d * CAP + e] * HID + f];
  float d0 = 1.0f / sqrtf((float)(cntu + selfc[d] + 2));
  float h = tanhf(d0 * acc + bias[f]);
  H[d * HID + f] = h;
  float pv = p[f];
  red[f] = h * pv;
  red2[f] = pv * pv;
  __syncthreads();
  for (int s = 64; s > 0; s >>= 1) {
    if (f < s) { red[f] += red[f + s]; red2[f] += red2[f + s]; }
    __syncthreads();
  }
  if (f == 0) score[d] = tanhf(red[0] * (1.0f / sqrtf(red2[0])));
}

// Top-K, one 256-thread block. Radix-select with hierarchical set compaction
// between passes; final index-ordered ballot compaction (verified) over score[].
__global__ __launch_bounds__(256) void k_topk(const float* __restrict__ score, int n, int K,
                                              int* __restrict__ perm, float* __restrict__ gatec,
                                              int* __restrict__ inv) {
  __shared__ unsigned setA[N0];
  __shared__ unsigned setB[N0];
  __shared__ int hist[256];
  __shared__ int sscan[257];
  __shared__ unsigned pfx_sh;
  __shared__ int rem_sh;
  __shared__ int cnt_sh;
  int t = threadIdx.x;
  for (int i = t; i < n; i += 256) setA[i] = fkey(score[i]);
  __syncthreads();

  unsigned prefix = 0; int rem = K; int m = n;
  unsigned* cur = setA; unsigned* nxt = setB;
  for (int pass = 3; pass >= 0; --pass) {
    hist[t] = 0;
    __syncthreads();
    for (int i = t; i < m; i += 256) atomicAdd(&hist[(cur[i] >> (pass * 8)) & 255], 1);
    __syncthreads();
    sscan[t] = hist[t];
    if (t == 0) sscan[256] = 0;
    __syncthreads();
    for (int off = 1; off < 256; off <<= 1) {
      int add = (t + off < 256) ? sscan[t + off] : 0;
      __syncthreads();
      sscan[t] += add;
      __syncthreads();
    }
    if (sscan[t] >= rem && sscan[t + 1] < rem) {
      pfx_sh = prefix | ((unsigned)t << (pass * 8));
      rem_sh = rem - sscan[t + 1];
    }
    __syncthreads();
    prefix = pfx_sh; rem = rem_sh;
    if (pass > 0) {
      unsigned dg = (prefix >> (pass * 8)) & 255u;
      if (t == 0) cnt_sh = 0;
      __syncthreads();
      int lane = t & 63;
      unsigned long long below = (lane == 0) ? 0ull : (~0ull >> (64 - lane));
      for (int c0 = 0; c0 < m; c0 += 256) {
        int i = c0 + t;
        unsigned u = (i < m) ? cur[i] : 0u;
        bool match = (i < m) && (((u >> (pass * 8)) & 255u) == dg);
        unsigned long long mm = __ballot(match);
        int cw = (int)__popcll(mm);
        int basew = 0;
        if (lane == 0 && cw) basew = atomicAdd(&cnt_sh, cw);
        basew = __shfl(basew, 0);
        if (match) nxt[basew + (int)__popcll(mm & below)] = u;
      }
      __syncthreads();
      m = cnt_sh;
      unsigned* tmp = cur; cur = nxt; nxt = tmp;
    }
  }
  unsigned uthr = prefix;
  int c_gt = K - rem;
  if (t >= 64) return;
  int lane = t;
  unsigned long long below = (lane == 0) ? 0ull : (~0ull >> (64 - lane));
  int base_gt = 0, base_eq = 0;
  for (int chunk = 0; chunk < n; chunk += 64) {
    int i = chunk + lane;
    bool valid = (i < n);
    unsigned u = valid ? fkey(score[i]) : 0u;
    bool isgt = valid && (u > uthr);
    bool iseq = valid && (u == uthr);
    unsigned long long mg = __ballot(isgt);
    unsigned long long me = __ballot(iseq);
    if (isgt) {
      int pos = base_gt + (int)__popcll(mg & below);
      perm[pos] = i; gatec[pos] = inv_fkey(u); inv[i] = pos;
    } else if (iseq) {
      int er = base_eq + (int)__popcll(me & below);
      if (er < rem) { int pos = c_gt + er; perm[pos] = i; gatec[pos] = inv_fkey(u); inv[i] = pos; }
    }
    base_gt += (int)__popcll(mg);
    base_eq += (int)__popcll(me);
  }
}

// A0 augment restricted to selected nodes, fused with the +2*A' term.
__global__ void k_pairs(const int* __restrict__ cnt_in, const int* __restrict__ col_in,
                        const int* __restrict__ cnt_out, const int* __restrict__ col_out,
                        const int* __restrict__ inv, float* __restrict__ A1) {
  __shared__ int outl[CAP], inl[CAP], invo[CAP], invi[CAP];
  int k = blockIdx.x, t = threadIdx.x;
  int no = cnt_out[k]; if (no > CAP) no = CAP;
  int ni = cnt_in[k];  if (ni > CAP) ni = CAP;
  if (t < no) { int i = col_out[k * CAP + t]; outl[t] = i; invo[t] = inv[i]; }
  if (t < ni) { int j = col_in[k * CAP + t];  inl[t] = j;  invi[t] = inv[j]; }
  __syncthreads();
  int invk = inv[k];
  if (t < ni && invk >= 0) {
    int jj = invi[t];
    if (jj >= 0) atomicAdd(&A1[(size_t)invk * LD1 + jj], 2.0f);   // edge term (2*A')
  }
  for (int a = t; a < no; a += blockDim.x) {
    int i = outl[a], ii = invo[a];
    if (ii < 0) continue;
    for (int b = 0; b < ni; ++b) {
      int jj = invi[b];
      if (jj >= 0 && i != inl[b]) atomicAdd(&A1[(size_t)ii * LD1 + jj], 1.0f);
    }
  }
}

__global__ void k_rowsum(const float* __restrict__ A, int n, int ld, float* __restrict__ dis) {
  __shared__ float red[256];
  int r = blockIdx.x, t = threadIdx.x;
  float acc = 0.0f;
  for (int c = t; c < n; c += 256) acc += A[(size_t)r * ld + c];
  red[t] = acc; __syncthreads();
  for (int s = 128; s > 0; s >>= 1) { if (t < s) red[t] += red[t + s]; __syncthreads(); }
  if (t == 0) dis[r] = 1.0f / sqrtf(red[0] + 2.0f);
}

// Column compaction to int16: Ac[k][b] = (short)A1[k][perm2[b]]  (b < K2N, else 0)
// A1/A2 entries are small non-negative integers (2-path counts) — int16-exact.
__global__ __launch_bounds__(256) void k_cmp(const float* __restrict__ A1,
                                             const int* __restrict__ perm2,
                                             short* __restrict__ Ac) {
  __shared__ int q[K2N];
  int k = blockIdx.x, t = threadIdx.x;
  for (int i = t; i < K2N; i += 256) {
    int v = perm2[i];
    if (v < 0) v = 0;
    if (v >= K1N) v = K1N - 1;
    q[i] = v;
  }
  __syncthreads();
  const float* row = A1 + (size_t)k * LD1;
  short* dst = Ac + (size_t)k * LD2;
  for (int b = t; b < LD2; b += 256) dst[b] = (b < K2N) ? (short)row[q[b]] : (short)0;
}

// A2[a][b] = (b!=a) ? sum_k A1[qa][k]*Ac[k][b] + 2*A1[qa][perm2[b]] : 0
// int16 Ac (integer-exact), ILP-8; + fused dis2[a] = 1/sqrt(rowsum(A2[a]) + 2)
__global__ __launch_bounds__(256) void k_sq2(const float* __restrict__ A1,
                                             const short* __restrict__ Ac,
                                             const int* __restrict__ perm2,
                                             float* __restrict__ A2,
                                             float* __restrict__ dis2) {
  __shared__ int klist[K1N];
  __shared__ float wlist[K1N];
  __shared__ int nnz_sh;
  __shared__ float wred[4];
  int a = blockIdx.x, t = threadIdx.x;
  int qa = perm2[a];
  if (qa < 0) qa = 0;
  if (qa >= K1N) qa = K1N - 1;
  if (t == 0) nnz_sh = 0;
  __syncthreads();
  const float* arow = A1 + (size_t)qa * LD1;
  for (int c = t; c < K1N; c += 256) {
    float w = arow[c];
    if (w != 0.0f) { int p = atomicAdd(&nnz_sh, 1); klist[p] = c; wlist[p] = w; }
  }
  __syncthreads();
  int nnz = nnz_sh;
  int c0 = t * 4;
  bool active = (c0 < LD2);
  float4 acc = make_float4(0.f, 0.f, 0.f, 0.f);
  int p = 0;
  for (; p + 8 <= nnz; p += 8) {   // 8 independent L2 loads in flight (8B each)
    int kk[8]; float ww[8];
#pragma unroll
    for (int j = 0; j < 8; ++j) { kk[j] = klist[p + j]; ww[j] = wlist[p + j]; }
    if (active) {
      short4 v[8];
#pragma unroll
      for (int j = 0; j < 8; ++j) v[j] = *(const short4*)&Ac[(size_t)kk[j] * LD2 + c0];
#pragma unroll
      for (int j = 0; j < 8; ++j) {
        acc.x += ww[j] * (float)v[j].x;
        acc.y += ww[j] * (float)v[j].y;
        acc.z += ww[j] * (float)v[j].z;
        acc.w += ww[j] * (float)v[j].w;
      }
    }
  }
  for (; p < nnz; ++p) {
    int k = klist[p]; float w = wlist[p];
    if (active) {
      short4 v = *(const short4*)&Ac[(size_t)k * LD2 + c0];
      acc.x += w * (float)v.x; acc.y += w * (float)v.y;
      acc.z += w * (float)v.z; acc.w += w * (float)v.w;
    }
  }
  float rsum = 0.0f;
  if (active) {
    float accv[4] = {acc.x, acc.y, acc.z, acc.w};
    float outv[4];
#pragma unroll
    for (int j = 0; j < 4; ++j) {
      int col = c0 + j;
      float v = 0.0f;
      if (col < K2N && col != a) {
        int qb = perm2[col];
        if (qb < 0) qb = 0;
        if (qb >= K1N) qb = K1N - 1;
        v = accv[j] + 2.0f * arow[qb];
      }
      outv[j] = v;
      rsum += v;
    }
    *(float4*)&A2[(size_t)a * LD2 + c0] = make_float4(outv[0], outv[1], outv[2], outv[3]);
  }
  for (int off = 32; off > 0; off >>= 1) rsum += __shfl_down(rsum, off);
  if ((t & 63) == 0) wred[t >> 6] = rsum;
  __syncthreads();
  if (t == 0) dis2[a] = 1.0f / sqrtf(wred[0] + wred[1] + wred[2] + wred[3] + 2.0f);
}

// Row-sparse GCN aggregation + epilogue (+ optional fused score) — 128 threads,
// gather loop ILP-8 (ascending-order adds preserved → bit-identical).
__global__ __launch_bounds__(128) void k_spmv(const float* __restrict__ A, int ncols, int ld,
                                              const float* __restrict__ Ysc,
                                              const float* __restrict__ dis,
                                              const float* __restrict__ bias,
                                              const float* __restrict__ p,
                                              float* __restrict__ H,
                                              float* __restrict__ score, int act) {
  __shared__ int klist[K1N];
  __shared__ float wlist[K1N];
  __shared__ int cntw[2];
  __shared__ float red[HID];
  __shared__ float red2[HID];
  int r = blockIdx.x, t = threadIdx.x;
  const float* arow = A + (size_t)r * ld;
  int wid = t >> 6, lane = t & 63;
  unsigned long long below = (lane == 0) ? 0ull : (~0ull >> (64 - lane));
  int base = 0;
  for (int c0 = 0; c0 < ncols; c0 += 128) {
    int col = c0 + t;
    float w = (col < ncols) ? arow[col] : 0.0f;
    bool nz = (w != 0.0f);
    unsigned long long m = __ballot(nz);
    if (lane == 0) cntw[wid] = (int)__popcll(m);
    __syncthreads();
    int pos = base + (wid ? cntw[0] : 0) + (int)__popcll(m & below);
    if (nz) { klist[pos] = col; wlist[pos] = w; }
    base += cntw[0] + cntw[1];
    __syncthreads();
  }
  int nnz = base;
  float acc = 0.0f;
  int pp = 0;
  for (; pp + 8 <= nnz; pp += 8) {
    float y[8];
#pragma unroll
    for (int j = 0; j < 8; ++j) y[j] = Ysc[(size_t)klist[pp + j] * HID + t];
#pragma unroll
    for (int j = 0; j < 8; ++j) acc += wlist[pp + j] * y[j];
  }
  for (; pp < nnz; ++pp) acc += wlist[pp] * Ysc[(size_t)klist[pp] * HID + t];
  float zv = dis[r] * (acc + 2.0f * Ysc[(size_t)r * HID + t]) + bias[t];
  float h = act ? tanhf(zv) : zv;
  H[(size_t)r * HID + t] = h;
  if (p) {
    float pv = p[t];
    red[t] = h * pv;
    red2[t] = pv * pv;
    __syncthreads();
    for (int s = 64; s > 0; s >>= 1) {
      if (t < s) { red[t] += red[t + s]; red2[t] += red2[t + s]; }
      __syncthreads();
    }
    if (t == 0) score[r] = tanhf(red[0] * (1.0f / sqrtf(red2[0])));
  }
}

// Yfsc[i] = dis0[i] * ((h0[i] + scatter(u1b)) @ W_up1)   [N0 x 3]
__global__ void k_yf(const float* __restrict__ h0, const float* __restrict__ u1b,
                     const int* __restrict__ inv1, const float* __restrict__ Wup1,
                     const int* __restrict__ cnt_in, const int* __restrict__ selfc,
                     float* __restrict__ Yfsc) {
  __shared__ float red[3][HID];
  int i = blockIdx.x, t = threadIdx.x;
  float v = h0[i * HID + t];
  int ii = inv1[i];
  if (ii >= 0 && ii < K1N) v += u1b[ii * HID + t];
#pragma unroll
  for (int c = 0; c < 3; ++c) red[c][t] = v * Wup1[t * 3 + c];
  __syncthreads();
  for (int s = 64; s > 0; s >>= 1) {
    if (t < s) { red[0][t] += red[0][t + s]; red[1][t] += red[1][t + s]; red[2][t] += red[2][t + s]; }
    __syncthreads();
  }
  if (t < 3) {
    float d0 = 1.0f / sqrtf((float)(cnt_in[i] + selfc[i] + 2));
    Yfsc[i * 3 + t] = d0 * red[t][0];
  }
}

__global__ void k_final(const float* __restrict__ Yfsc, const int* __restrict__ cnt_in,
                        const int* __restrict__ col_in, const int* __restrict__ selfc,
                        const float* __restrict__ bup1, const float* __restrict__ z,
                        float* __restrict__ out) {
  int idx = blockIdx.x * blockDim.x + threadIdx.x;
  if (idx >= N0 * 3) return;
  int d = idx / 3, c = idx - d * 3;
  int cntu = cnt_in[d];
  int cnt = cntu > CAP ? CAP : cntu;
  float acc = (2.0f + (float)selfc[d]) * Yfsc[d * 3 + c];
  for (int e = 0; e < cnt; ++e) acc += Yfsc[col_in[d * CAP + e] * 3 + c];
  float d0 = 1.0f / sqrtf((float)(cntu + selfc[d] + 2));
  out[idx] = d0 * acc + bup1[c] + 0.1f * z[idx];
}

extern "C" void kernel_launch(void* const* d_in, const int* in_sizes, int n_in,
                              void* d_out, int out_size, void* d_ws, size_t ws_size,
                              hipStream_t stream) {
  const float* x   = (const float*)d_in[0];
  const float* z   = (const float*)d_in[1];
  const float* Wd0 = (const float*)d_in[2];
  const float* bd0 = (const float*)d_in[3];
  const float* Wd1 = (const float*)d_in[4];
  const float* bd1 = (const float*)d_in[5];
  const float* Wd2 = (const float*)d_in[6];
  const float* bd2 = (const float*)d_in[7];
  const float* p1  = (const float*)d_in[8];
  const float* p2  = (const float*)d_in[9];
  const float* Wu0 = (const float*)d_in[10];
  const float* bu0 = (const float*)d_in[11];
  const float* Wu1 = (const float*)d_in[12];
  const float* bu1 = (const float*)d_in[13];
  const int*   ei  = (const int*)d_in[14];

  if (ws_size < F_END * sizeof(float)) return;

  float* W     = (float*)d_ws;
  float* A1    = W + F_A1;
  short* Ac    = (short*)(W + F_SCR);
  float* A2    = W + F_A2;
  float* Ysc   = W + F_YSC;
  float* h0    = W + F_H0;
  float* h1    = W + F_H1;
  float* h2    = W + F_H2;
  float* u1b   = W + F_U1B;
  float* Yfsc  = W + F_YF;
  float* score = W + F_SCORE;
  float* gate1 = W + F_GATE1;
  float* gate2 = W + F_GATE2;
  float* dis1  = W + F_DIS1;
  float* dis2  = W + F_DIS2;
  int* perm1   = (int*)(W + F_PERM1);
  int* perm2   = (int*)(W + F_PERM2);
  int* inv1    = (int*)(W + F_INV1);
  int* inv2    = (int*)(W + F_INV2);
  int* cnt_in  = (int*)(W + F_CNTI);
  int* cnt_out = (int*)(W + F_CNTO);
  int* selfc   = (int*)(W + F_SELF);
  int* col_in  = (int*)(W + F_CI);
  int* col_out = (int*)(W + F_CO);
  float* out   = (float*)d_out;

  // ---- init (single fused fill) ----
  k_init<<<1024, 256, 0, stream>>>(A1, gate1, perm1, inv1, cnt_in, out + N0 * 3);

  // ---- edge lists ----
  k_count<<<(E0 + 255) / 256, 256, 0, stream>>>(ei, cnt_in, cnt_out, selfc, col_in, col_out);

  // ---- level 0 GCN + pool-1 score ----
  k_yw2<<<(N0 + BM - 1) / BM, 256, 0, stream>>>(x, nullptr, nullptr, 32, N0, N0, Wd0,
                                                nullptr, nullptr, nullptr, cnt_in, selfc, Ysc);
  k_gcn_sparse<<<N0, HID, 0, stream>>>(Ysc, cnt_in, col_in, selfc, bd0, p1, h0, score);
  k_topk<<<1, 256, 0, stream>>>(score, N0, K1N, perm1, gate1, inv1);

  // ---- A1 = augment(A0)[perm1][:,perm1] ----
  k_pairs<<<N0, 128, 0, stream>>>(cnt_in, col_in, cnt_out, col_out, inv1, A1);
  k_rowsum<<<K1N, 256, 0, stream>>>(A1, K1N, LD1, dis1);

  // ---- level 1 GCN (sparse) + pool-2 score fused ----
  k_yw2<<<(K1N + BM - 1) / BM, 256, 0, stream>>>(h0, nullptr, nullptr, HID, N0, K1N, Wd1,
                                                 perm1, gate1, dis1, nullptr, nullptr, Ysc);
  k_spmv<<<K1N, 128, 0, stream>>>(A1, K1N, LD1, Ysc, dis1, bd1, p2, h1, score, 1);
  k_topk<<<1, 256, 0, stream>>>(score, K1N, K2N, perm2, gate2, inv2);

  // ---- A2 = augment(A1)[perm2][:,perm2] (int16 Ac + fused dis2) ----
  k_cmp<<<K1N, 256, 0, stream>>>(A1, perm2, Ac);
  k_sq2<<<K2N, 256, 0, stream>>>(A1, Ac, perm2, A2, dis2);

  // ---- level 2 GCN (sparse) ----
  k_yw2<<<(K2N + BM - 1) / BM, 256, 0, stream>>>(h1, nullptr, nullptr, HID, K1N, K2N, Wd2,
                                                 perm2, gate2, dis2, nullptr, nullptr, Ysc);
  k_spmv<<<K2N, 128, 0, stream>>>(A2, K2N, LD2, Ysc, dis2, bd2, nullptr, h2, nullptr, 1);

  // ---- up path (combine fused into staging) ----
  k_yw2<<<(K1N + BM - 1) / BM, 256, 0, stream>>>(h1, h2, inv2, HID, K1N, K1N, Wu0,
                                                 nullptr, nullptr, dis1, nullptr, nullptr, Ysc);
  k_spmv<<<K1N, 128, 0, stream>>>(A1, K1N, LD1, Ysc, dis1, bu0, nullptr, u1b, nullptr, 1);

  // ---- final ----
  k_yf<<<N0, HID, 0, stream>>>(h0, u1b, inv1, Wu1, cnt_in, selfc, Yfsc);
  k_final<<<(N0 * 3 + 255) / 256, 256, 0, stream>>>(Yfsc, cnt_in, col_in, selfc, bu1, z, out);
}

// Round 12
// 290.597 us; speedup vs baseline: 1.0622x; 1.0265x over previous
//
#include <hip/hip_runtime.h>
#include <hip/hip_bf16.h>

#define N0   3000
#define E0   48000
#define K1N  1500
#define K2N  750
#define HID  128
#define CAP  128
#define LD1  1536  // padded leading dim for A1
#define LD2  768   // padded leading dim for A2/Ac
#define BM   32    // row-tile for k_yw2
#define ATS  36    // transposed X-tile stride (BM+4, bank-spread)
#define RCAP 1536  // CSR row capacity (>= max possible nnz = K1N)

__device__ __forceinline__ unsigned fkey(float f) {
  unsigned u = __float_as_uint(f);
  return (u & 0x80000000u) ? ~u : (u | 0x80000000u);
}
__device__ __forceinline__ float inv_fkey(unsigned u) {
  unsigned v = (u & 0x80000000u) ? (u & 0x7FFFFFFFu) : ~u;
  return __uint_as_float(v);
}

// ---------------- workspace layout (float units) ----------------
constexpr size_t F_A1    = 0;                          // K1N*LD1
constexpr size_t F_SCR   = F_A1 + (size_t)K1N * LD1;   // Ac (int16) = K1N*LD2 shorts
constexpr size_t SCR_SZ  = 1155072;                    // plenty
constexpr size_t F_A2    = F_SCR + SCR_SZ;             // K2N*LD2
constexpr size_t F_YSC   = F_A2 + (size_t)K2N * LD2;   // N0*HID
constexpr size_t F_H0    = F_YSC + (size_t)N0 * HID;   // N0*HID
constexpr size_t F_H1    = F_H0 + (size_t)N0 * HID;    // K1N*HID
constexpr size_t F_H2    = F_H1 + (size_t)K1N * HID;   // K2N*HID
constexpr size_t F_U1    = F_H2 + (size_t)K2N * HID;   // (hole, kept for layout)
constexpr size_t F_U1B   = F_U1 + (size_t)K1N * HID;   // K1N*HID
constexpr size_t F_YF    = F_U1B + (size_t)K1N * HID;  // N0*3
constexpr size_t F_SCORE = F_YF + (size_t)N0 * 3;      // N0
constexpr size_t F_GATE1 = F_SCORE + N0;               // K1N  } contiguous zero fill
constexpr size_t F_GATE2 = F_GATE1 + K1N;              // K2N  }
constexpr size_t F_DIS0  = F_GATE2 + K2N;              // (unused)
constexpr size_t F_DIS1  = F_DIS0 + N0;                // K1N
constexpr size_t F_DIS2  = F_DIS1 + K1N;               // K2N
constexpr size_t F_PERM1 = F_DIS2 + K2N;               // K1N (int) } contiguous 0 fill
constexpr size_t F_PERM2 = F_PERM1 + K1N;              // K2N (int) }
constexpr size_t F_INV1  = F_PERM2 + K2N;              // N0  (int) } contiguous -1 fill
constexpr size_t F_INV2  = F_INV1 + N0;                // K1N (int) }
constexpr size_t F_CNTI  = F_INV2 + K1N;               // N0  (int) } contiguous 0 fill
constexpr size_t F_CNTO  = F_CNTI + N0;                // N0  (int) }
constexpr size_t F_SELF  = F_CNTO + N0;                // N0  (int) }
constexpr size_t F_CI    = F_SELF + N0;                // N0*CAP (int)
constexpr size_t F_CO    = F_CI + (size_t)N0 * CAP;    // N0*CAP (int)
constexpr size_t F_CSRN  = F_CO + (size_t)N0 * CAP;    // K1N (int)
constexpr size_t F_CSRK  = F_CSRN + K1N;               // K1N*RCAP (int)
constexpr size_t F_CSRW  = F_CSRK + (size_t)K1N * RCAP;// K1N*RCAP (float)
constexpr size_t F_END   = F_CSRW + (size_t)K1N * RCAP;

// ---------------- init: all fills fused (1 dispatch) ----------------
__global__ void k_init(float* __restrict__ A1, float* __restrict__ gate,
                       int* __restrict__ perm, int* __restrict__ inv,
                       int* __restrict__ cnt, float* __restrict__ outlab) {
  int i = blockIdx.x * blockDim.x + threadIdx.x, st = gridDim.x * blockDim.x;
  for (int j = i; j < K1N * LD1; j += st) A1[j] = 0.0f;
  for (int j = i; j < K1N + K2N; j += st) gate[j] = 0.0f;
  for (int j = i; j < K1N + K2N; j += st) perm[j] = 0;
  for (int j = i; j < N0 + K1N; j += st) inv[j] = -1;
  for (int j = i; j < 3 * N0; j += st) cnt[j] = 0;
  for (int j = i; j < N0 * 29; j += st) outlab[j] = 0.0f;
}

// Build per-node edge lists: col_in[d] = srcs of non-self in-edges, col_out[s] = dsts.
__global__ void k_count(const int* __restrict__ ei, int* cnt_in, int* cnt_out, int* selfc,
                        int* col_in, int* col_out) {
  int e = blockIdx.x * blockDim.x + threadIdx.x;
  if (e >= E0) return;
  int s = ei[e], d = ei[E0 + e];
  if (s == d) { atomicAdd(&selfc[d], 1); return; }
  int a = atomicAdd(&cnt_in[d], 1);
  if (a < CAP) col_in[d * CAP + a] = s;
  int b = atomicAdd(&cnt_out[s], 1);
  if (b < CAP) col_out[s * CAP + b] = d;
}

// Ysc[row][f] = scale(row) * sum_k Xeff[src(row)][k] * Wm[k][f]
__global__ __launch_bounds__(256) void k_yw2(const float* __restrict__ X,
                                             const float* __restrict__ X2,
                                             const int* __restrict__ inv2c,
                                             int Kin, int nsrc, int n,
                                             const float* __restrict__ Wm,
                                             const int* __restrict__ perm,
                                             const float* __restrict__ gate,
                                             const float* __restrict__ dis,
                                             const int* __restrict__ cntd,
                                             const int* __restrict__ selfd,
                                             float* __restrict__ Ysc) {
  __shared__ float Wt[32 * HID];   // 16 KB, [kk][f]
  __shared__ float Xt[32 * ATS];   // 4.6 KB, [kk][row] transposed
  int t = threadIdx.x;
  int r0 = blockIdx.x * BM;
  int f4 = (t & 31) * 4;
  int rg = t >> 5;                 // 0..7 -> rows r0 + rg*4 + {0..3}
  float4 acc0 = {0,0,0,0}, acc1 = {0,0,0,0}, acc2 = {0,0,0,0}, acc3 = {0,0,0,0};
  for (int kb = 0; kb < Kin; kb += 32) {
    {
      const float4* src = (const float4*)(Wm + (size_t)kb * HID);
      float4* dst = (float4*)Wt;
#pragma unroll
      for (int i = 0; i < 4; ++i) dst[i * 256 + t] = src[i * 256 + t];
    }
    {
      int j = t >> 3;
      int k4 = (t & 7) * 4;
      int r = r0 + j;
      int src_row = (r < n) ? r : (n - 1);
      if (perm) {
        int s = perm[src_row];
        if (s < 0) s = 0;
        if (s >= nsrc) s = nsrc - 1;
        src_row = s;
      }
      float4 xv = *(const float4*)(X + (size_t)src_row * Kin + kb + k4);
      if (X2) {
        int ii = inv2c[src_row];
        if (ii >= 0 && ii < K2N) {
          float4 x2 = *(const float4*)(X2 + (size_t)ii * Kin + kb + k4);
          xv.x += x2.x; xv.y += x2.y; xv.z += x2.z; xv.w += x2.w;
        }
      }
      Xt[(k4 + 0) * ATS + j] = xv.x;
      Xt[(k4 + 1) * ATS + j] = xv.y;
      Xt[(k4 + 2) * ATS + j] = xv.z;
      Xt[(k4 + 3) * ATS + j] = xv.w;
    }
    __syncthreads();
#pragma unroll 4
    for (int kk = 0; kk < 32; ++kk) {
      float4 y = *(const float4*)&Wt[kk * HID + f4];
      float4 a = *(const float4*)&Xt[kk * ATS + rg * 4];
      acc0.x += a.x * y.x; acc0.y += a.x * y.y; acc0.z += a.x * y.z; acc0.w += a.x * y.w;
      acc1.x += a.y * y.x; acc1.y += a.y * y.y; acc1.z += a.y * y.z; acc1.w += a.y * y.w;
      acc2.x += a.z * y.x; acc2.y += a.z * y.y; acc2.z += a.z * y.z; acc2.w += a.z * y.w;
      acc3.x += a.w * y.x; acc3.y += a.w * y.y; acc3.z += a.w * y.z; acc3.w += a.w * y.w;
    }
    __syncthreads();
  }
  int r = r0 + rg * 4;
  float4* accs[4] = {&acc0, &acc1, &acc2, &acc3};
#pragma unroll
  for (int j = 0; j < 4; ++j) {
    int row = r + j;
    if (row >= n) continue;
    float g = gate ? gate[row] : 1.0f;
    float d = dis ? dis[row] : (1.0f / sqrtf((float)(cntd[row] + selfd[row] + 2)));
    float s = d * g;
    float4 a = *accs[j];
    *(float4*)&Ysc[(size_t)row * HID + f4] = make_float4(s * a.x, s * a.y, s * a.z, s * a.w);
  }
}

// Level-0 sparse GCN + fused score (128 threads = 2 waves)
__global__ void k_gcn_sparse(const float* __restrict__ Ysc, const int* __restrict__ cnt_in,
                             const int* __restrict__ col_in, const int* __restrict__ selfc,
                             const float* __restrict__ bias, const float* __restrict__ p,
                             float* __restrict__ H, float* __restrict__ score) {
  __shared__ float red[HID];
  __shared__ float red2[HID];
  int d = blockIdx.x, f = threadIdx.x;
  int cntu = cnt_in[d];
  int cnt = cntu > CAP ? CAP : cntu;
  float acc = (2.0f + (float)selfc[d]) * Ysc[d * HID + f];
  for (int e = 0; e < cnt; ++e) acc += Ysc[col_in[d * CAP + e] * HID + f];
  float d0 = 1.0f / sqrtf((float)(cntu + selfc[d] + 2));
  float h = tanhf(d0 * acc + bias[f]);
  H[d * HID + f] = h;
  float pv = p[f];
  red[f] = h * pv;
  red2[f] = pv * pv;
  __syncthreads();
  for (int s = 64; s > 0; s >>= 1) {
    if (f < s) { red[f] += red[f + s]; red2[f] += red2[f + s]; }
    __syncthreads();
  }
  if (f == 0) score[d] = tanhf(red[0] * (1.0f / sqrtf(red2[0])));
}

// Top-K, one 256-thread block. Radix-select with hierarchical set compaction
// between passes; final index-ordered ballot compaction (verified) over score[].
__global__ __launch_bounds__(256) void k_topk(const float* __restrict__ score, int n, int K,
                                              int* __restrict__ perm, float* __restrict__ gatec,
                                              int* __restrict__ inv) {
  __shared__ unsigned setA[N0];
  __shared__ unsigned setB[N0];
  __shared__ int hist[256];
  __shared__ int sscan[257];
  __shared__ unsigned pfx_sh;
  __shared__ int rem_sh;
  __shared__ int cnt_sh;
  int t = threadIdx.x;
  for (int i = t; i < n; i += 256) setA[i] = fkey(score[i]);
  __syncthreads();

  unsigned prefix = 0; int rem = K; int m = n;
  unsigned* cur = setA; unsigned* nxt = setB;
  for (int pass = 3; pass >= 0; --pass) {
    hist[t] = 0;
    __syncthreads();
    for (int i = t; i < m; i += 256) atomicAdd(&hist[(cur[i] >> (pass * 8)) & 255], 1);
    __syncthreads();
    sscan[t] = hist[t];
    if (t == 0) sscan[256] = 0;
    __syncthreads();
    for (int off = 1; off < 256; off <<= 1) {
      int add = (t + off < 256) ? sscan[t + off] : 0;
      __syncthreads();
      sscan[t] += add;
      __syncthreads();
    }
    if (sscan[t] >= rem && sscan[t + 1] < rem) {
      pfx_sh = prefix | ((unsigned)t << (pass * 8));
      rem_sh = rem - sscan[t + 1];
    }
    __syncthreads();
    prefix = pfx_sh; rem = rem_sh;
    if (pass > 0) {
      unsigned dg = (prefix >> (pass * 8)) & 255u;
      if (t == 0) cnt_sh = 0;
      __syncthreads();
      int lane = t & 63;
      unsigned long long below = (lane == 0) ? 0ull : (~0ull >> (64 - lane));
      for (int c0 = 0; c0 < m; c0 += 256) {
        int i = c0 + t;
        unsigned u = (i < m) ? cur[i] : 0u;
        bool match = (i < m) && (((u >> (pass * 8)) & 255u) == dg);
        unsigned long long mm = __ballot(match);
        int cw = (int)__popcll(mm);
        int basew = 0;
        if (lane == 0 && cw) basew = atomicAdd(&cnt_sh, cw);
        basew = __shfl(basew, 0);
        if (match) nxt[basew + (int)__popcll(mm & below)] = u;
      }
      __syncthreads();
      m = cnt_sh;
      unsigned* tmp = cur; cur = nxt; nxt = tmp;
    }
  }
  unsigned uthr = prefix;
  int c_gt = K - rem;
  if (t >= 64) return;
  int lane = t;
  unsigned long long below = (lane == 0) ? 0ull : (~0ull >> (64 - lane));
  int base_gt = 0, base_eq = 0;
  for (int chunk = 0; chunk < n; chunk += 64) {
    int i = chunk + lane;
    bool valid = (i < n);
    unsigned u = valid ? fkey(score[i]) : 0u;
    bool isgt = valid && (u > uthr);
    bool iseq = valid && (u == uthr);
    unsigned long long mg = __ballot(isgt);
    unsigned long long me = __ballot(iseq);
    if (isgt) {
      int pos = base_gt + (int)__popcll(mg & below);
      perm[pos] = i; gatec[pos] = inv_fkey(u); inv[i] = pos;
    } else if (iseq) {
      int er = base_eq + (int)__popcll(me & below);
      if (er < rem) { int pos = c_gt + er; perm[pos] = i; gatec[pos] = inv_fkey(u); inv[i] = pos; }
    }
    base_gt += (int)__popcll(mg);
    base_eq += (int)__popcll(me);
  }
}

// A0 augment restricted to selected nodes, fused with the +2*A' term.
__global__ void k_pairs(const int* __restrict__ cnt_in, const int* __restrict__ col_in,
                        const int* __restrict__ cnt_out, const int* __restrict__ col_out,
                        const int* __restrict__ inv, float* __restrict__ A1) {
  __shared__ int outl[CAP], inl[CAP], invo[CAP], invi[CAP];
  int k = blockIdx.x, t = threadIdx.x;
  int no = cnt_out[k]; if (no > CAP) no = CAP;
  int ni = cnt_in[k];  if (ni > CAP) ni = CAP;
  if (t < no) { int i = col_out[k * CAP + t]; outl[t] = i; invo[t] = inv[i]; }
  if (t < ni) { int j = col_in[k * CAP + t];  inl[t] = j;  invi[t] = inv[j]; }
  __syncthreads();
  int invk = inv[k];
  if (t < ni && invk >= 0) {
    int jj = invi[t];
    if (jj >= 0) atomicAdd(&A1[(size_t)invk * LD1 + jj], 2.0f);   // edge term (2*A')
  }
  for (int a = t; a < no; a += blockDim.x) {
    int i = outl[a], ii = invo[a];
    if (ii < 0) continue;
    for (int b = 0; b < ni; ++b) {
      int jj = invi[b];
      if (jj >= 0 && i != inl[b]) atomicAdd(&A1[(size_t)ii * LD1 + jj], 1.0f);
    }
  }
}

// Build CSR of A1 (ascending cols) + fused dis1 (integer-exact rowsum).
__global__ __launch_bounds__(128) void k_a1csr(const float* __restrict__ A1,
                                               int* __restrict__ csr_n,
                                               int* __restrict__ csr_k,
                                               float* __restrict__ csr_w,
                                               float* __restrict__ dis1) {
  __shared__ int cntw[2];
  __shared__ float wsum_sh[2];
  int r = blockIdx.x, t = threadIdx.x;
  const float* arow = A1 + (size_t)r * LD1;
  int wid = t >> 6, lane = t & 63;
  unsigned long long below = (lane == 0) ? 0ull : (~0ull >> (64 - lane));
  int base = 0;
  float wsum = 0.0f;
  int* gk = csr_k + (size_t)r * RCAP;
  float* gw = csr_w + (size_t)r * RCAP;
  for (int c0 = 0; c0 < K1N; c0 += 128) {
    int col = c0 + t;
    float w = (col < K1N) ? arow[col] : 0.0f;
    wsum += w;
    bool nz = (w != 0.0f);
    unsigned long long m = __ballot(nz);
    if (lane == 0) cntw[wid] = (int)__popcll(m);
    __syncthreads();
    int pos = base + (wid ? cntw[0] : 0) + (int)__popcll(m & below);
    if (nz) { gk[pos] = col; gw[pos] = w; }
    base += cntw[0] + cntw[1];
    __syncthreads();
  }
  for (int off = 32; off > 0; off >>= 1) wsum += __shfl_down(wsum, off);
  if (lane == 0) wsum_sh[wid] = wsum;
  __syncthreads();
  if (t == 0) {
    csr_n[r] = base;
    dis1[r] = 1.0f / sqrtf(wsum_sh[0] + wsum_sh[1] + 2.0f);
  }
}

// Column compaction to int16: Ac[k][b] = (short)A1[k][perm2[b]]  (b < K2N, else 0)
__global__ __launch_bounds__(256) void k_cmp(const float* __restrict__ A1,
                                             const int* __restrict__ perm2,
                                             short* __restrict__ Ac) {
  __shared__ int q[K2N];
  int k = blockIdx.x, t = threadIdx.x;
  for (int i = t; i < K2N; i += 256) {
    int v = perm2[i];
    if (v < 0) v = 0;
    if (v >= K1N) v = K1N - 1;
    q[i] = v;
  }
  __syncthreads();
  const float* row = A1 + (size_t)k * LD1;
  short* dst = Ac + (size_t)k * LD2;
  for (int b = t; b < LD2; b += 256) dst[b] = (b < K2N) ? (short)row[q[b]] : (short)0;
}

// A2[a][b] = (b!=a) ? sum_k A1[qa][k]*Ac[k][b] + 2*A1[qa][perm2[b]] : 0
// Row nonzeros loaded from precomputed CSR (coalesced); int16 Ac, ILP-8;
// + fused dis2[a] = 1/sqrt(rowsum(A2[a]) + 2)  (integer-exact)
__global__ __launch_bounds__(256) void k_sq2(const float* __restrict__ A1,
                                             const short* __restrict__ Ac,
                                             const int* __restrict__ perm2,
                                             const int* __restrict__ csr_n,
                                             const int* __restrict__ csr_k,
                                             const float* __restrict__ csr_w,
                                             float* __restrict__ A2,
                                             float* __restrict__ dis2) {
  __shared__ int klist[K1N];
  __shared__ float wlist[K1N];
  __shared__ float wred[4];
  int a = blockIdx.x, t = threadIdx.x;
  int qa = perm2[a];
  if (qa < 0) qa = 0;
  if (qa >= K1N) qa = K1N - 1;
  const float* arow = A1 + (size_t)qa * LD1;
  int nnz = csr_n[qa];
  {
    const int* gk = csr_k + (size_t)qa * RCAP;
    const float* gw = csr_w + (size_t)qa * RCAP;
    for (int c = t; c < nnz; c += 256) { klist[c] = gk[c]; wlist[c] = gw[c]; }
  }
  __syncthreads();
  int c0 = t * 4;
  bool active = (c0 < LD2);
  float4 acc = make_float4(0.f, 0.f, 0.f, 0.f);
  int p = 0;
  for (; p + 8 <= nnz; p += 8) {   // 8 independent L2 loads in flight
    int kk[8]; float ww[8];
#pragma unroll
    for (int j = 0; j < 8; ++j) { kk[j] = klist[p + j]; ww[j] = wlist[p + j]; }
    if (active) {
      short4 v[8];
#pragma unroll
      for (int j = 0; j < 8; ++j) v[j] = *(const short4*)&Ac[(size_t)kk[j] * LD2 + c0];
#pragma unroll
      for (int j = 0; j < 8; ++j) {
        acc.x += ww[j] * (float)v[j].x;
        acc.y += ww[j] * (float)v[j].y;
        acc.z += ww[j] * (float)v[j].z;
        acc.w += ww[j] * (float)v[j].w;
      }
    }
  }
  for (; p < nnz; ++p) {
    int k = klist[p]; float w = wlist[p];
    if (active) {
      short4 v = *(const short4*)&Ac[(size_t)k * LD2 + c0];
      acc.x += w * (float)v.x; acc.y += w * (float)v.y;
      acc.z += w * (float)v.z; acc.w += w * (float)v.w;
    }
  }
  float rsum = 0.0f;
  if (active) {
    float accv[4] = {acc.x, acc.y, acc.z, acc.w};
    float outv[4];
#pragma unroll
    for (int j = 0; j < 4; ++j) {
      int col = c0 + j;
      float v = 0.0f;
      if (col < K2N && col != a) {
        int qb = perm2[col];
        if (qb < 0) qb = 0;
        if (qb >= K1N) qb = K1N - 1;
        v = accv[j] + 2.0f * arow[qb];
      }
      outv[j] = v;
      rsum += v;
    }
    *(float4*)&A2[(size_t)a * LD2 + c0] = make_float4(outv[0], outv[1], outv[2], outv[3]);
  }
  for (int off = 32; off > 0; off >>= 1) rsum += __shfl_down(rsum, off);
  if ((t & 63) == 0) wred[t >> 6] = rsum;
  __syncthreads();
  if (t == 0) dis2[a] = 1.0f / sqrtf(wred[0] + wred[1] + wred[2] + wred[3] + 2.0f);
}

// CSR-based row-sparse GCN aggregation + epilogue (+ optional fused score).
// 128 threads; nonzero list loaded coalesced from CSR; gather ILP-8 ascending.
__global__ __launch_bounds__(128) void k_spmv_csr(const int* __restrict__ csr_n,
                                                  const int* __restrict__ csr_k,
                                                  const float* __restrict__ csr_w,
                                                  const float* __restrict__ Ysc,
                                                  const float* __restrict__ dis,
                                                  const float* __restrict__ bias,
                                                  const float* __restrict__ p,
                                                  float* __restrict__ H,
                                                  float* __restrict__ score, int act) {
  __shared__ int klist[K1N];
  __shared__ float wlist[K1N];
  __shared__ float red[HID];
  __shared__ float red2[HID];
  int r = blockIdx.x, t = threadIdx.x;
  int nnz = csr_n[r];
  {
    const int* gk = csr_k + (size_t)r * RCAP;
    const float* gw = csr_w + (size_t)r * RCAP;
    for (int i = t; i < nnz; i += 128) { klist[i] = gk[i]; wlist[i] = gw[i]; }
  }
  __syncthreads();
  float acc = 0.0f;
  int pp = 0;
  for (; pp + 8 <= nnz; pp += 8) {
    float y[8];
#pragma unroll
    for (int j = 0; j < 8; ++j) y[j] = Ysc[(size_t)klist[pp + j] * HID + t];
#pragma unroll
    for (int j = 0; j < 8; ++j) acc += wlist[pp + j] * y[j];
  }
  for (; pp < nnz; ++pp) acc += wlist[pp] * Ysc[(size_t)klist[pp] * HID + t];
  float zv = dis[r] * (acc + 2.0f * Ysc[(size_t)r * HID + t]) + bias[t];
  float h = act ? tanhf(zv) : zv;
  H[(size_t)r * HID + t] = h;
  if (p) {
    float pv = p[t];
    red[t] = h * pv;
    red2[t] = pv * pv;
    __syncthreads();
    for (int s = 64; s > 0; s >>= 1) {
      if (t < s) { red[t] += red[t + s]; red2[t] += red2[t + s]; }
      __syncthreads();
    }
    if (t == 0) score[r] = tanhf(red[0] * (1.0f / sqrtf(red2[0])));
  }
}

// Dense-scan spmv (used for A2, 768 cols): round-10 verified version.
__global__ __launch_bounds__(128) void k_spmv(const float* __restrict__ A, int ncols, int ld,
                                              const float* __restrict__ Ysc,
                                              const float* __restrict__ dis,
                                              const float* __restrict__ bias,
                                              const float* __restrict__ p,
                                              float* __restrict__ H,
                                              float* __restrict__ score, int act) {
  __shared__ int klist[K1N];
  __shared__ float wlist[K1N];
  __shared__ int cntw[2];
  __shared__ float red[HID];
  __shared__ float red2[HID];
  int r = blockIdx.x, t = threadIdx.x;
  const float* arow = A + (size_t)r * ld;
  int wid = t >> 6, lane = t & 63;
  unsigned long long below = (lane == 0) ? 0ull : (~0ull >> (64 - lane));
  int base = 0;
  for (int c0 = 0; c0 < ncols; c0 += 128) {
    int col = c0 + t;
    float w = (col < ncols) ? arow[col] : 0.0f;
    bool nz = (w != 0.0f);
    unsigned long long m = __ballot(nz);
    if (lane == 0) cntw[wid] = (int)__popcll(m);
    __syncthreads();
    int pos = base + (wid ? cntw[0] : 0) + (int)__popcll(m & below);
    if (nz) { klist[pos] = col; wlist[pos] = w; }
    base += cntw[0] + cntw[1];
    __syncthreads();
  }
  int nnz = base;
  float acc = 0.0f;
  int pp = 0;
  for (; pp + 8 <= nnz; pp += 8) {
    float y[8];
#pragma unroll
    for (int j = 0; j < 8; ++j) y[j] = Ysc[(size_t)klist[pp + j] * HID + t];
#pragma unroll
    for (int j = 0; j < 8; ++j) acc += wlist[pp + j] * y[j];
  }
  for (; pp < nnz; ++pp) acc += wlist[pp] * Ysc[(size_t)klist[pp] * HID + t];
  float zv = dis[r] * (acc + 2.0f * Ysc[(size_t)r * HID + t]) + bias[t];
  float h = act ? tanhf(zv) : zv;
  H[(size_t)r * HID + t] = h;
  if (p) {
    float pv = p[t];
    red[t] = h * pv;
    red2[t] = pv * pv;
    __syncthreads();
    for (int s = 64; s > 0; s >>= 1) {
      if (t < s) { red[t] += red[t + s]; red2[t] += red2[t + s]; }
      __syncthreads();
    }
    if (t == 0) score[r] = tanhf(red[0] * (1.0f / sqrtf(red2[0])));
  }
}

// Yfsc[i] = dis0[i] * ((h0[i] + scatter(u1b)) @ W_up1)   [N0 x 3]
__global__ void k_yf(const float* __restrict__ h0, const float* __restrict__ u1b,
                     const int* __restrict__ inv1, const float* __restrict__ Wup1,
                     const int* __restrict__ cnt_in, const int* __restrict__ selfc,
                     float* __restrict__ Yfsc) {
  __shared__ float red[3][HID];
  int i = blockIdx.x, t = threadIdx.x;
  float v = h0[i * HID + t];
  int ii = inv1[i];
  if (ii >= 0 && ii < K1N) v += u1b[ii * HID + t];
#pragma unroll
  for (int c = 0; c < 3; ++c) red[c][t] = v * Wup1[t * 3 + c];
  __syncthreads();
  for (int s = 64; s > 0; s >>= 1) {
    if (t < s) { red[0][t] += red[0][t + s]; red[1][t] += red[1][t + s]; red[2][t] += red[2][t + s]; }
    __syncthreads();
  }
  if (t < 3) {
    float d0 = 1.0f / sqrtf((float)(cnt_in[i] + selfc[i] + 2));
    Yfsc[i * 3 + t] = d0 * red[t][0];
  }
}

__global__ void k_final(const float* __restrict__ Yfsc, const int* __restrict__ cnt_in,
                        const int* __restrict__ col_in, const int* __restrict__ selfc,
                        const float* __restrict__ bup1, const float* __restrict__ z,
                        float* __restrict__ out) {
  int idx = blockIdx.x * blockDim.x + threadIdx.x;
  if (idx >= N0 * 3) return;
  int d = idx / 3, c = idx - d * 3;
  int cntu = cnt_in[d];
  int cnt = cntu > CAP ? CAP : cntu;
  float acc = (2.0f + (float)selfc[d]) * Yfsc[d * 3 + c];
  for (int e = 0; e < cnt; ++e) acc += Yfsc[col_in[d * CAP + e] * 3 + c];
  float d0 = 1.0f / sqrtf((float)(cntu + selfc[d] + 2));
  out[idx] = d0 * acc + bup1[c] + 0.1f * z[idx];
}

extern "C" void kernel_launch(void* const* d_in, const int* in_sizes, int n_in,
                              void* d_out, int out_size, void* d_ws, size_t ws_size,
                              hipStream_t stream) {
  const float* x   = (const float*)d_in[0];
  const float* z   = (const float*)d_in[1];
  const float* Wd0 = (const float*)d_in[2];
  const float* bd0 = (const float*)d_in[3];
  const float* Wd1 = (const float*)d_in[4];
  const float* bd1 = (const float*)d_in[5];
  const float* Wd2 = (const float*)d_in[6];
  const float* bd2 = (const float*)d_in[7];
  const float* p1  = (const float*)d_in[8];
  const float* p2  = (const float*)d_in[9];
  const float* Wu0 = (const float*)d_in[10];
  const float* bu0 = (const float*)d_in[11];
  const float* Wu1 = (const float*)d_in[12];
  const float* bu1 = (const float*)d_in[13];
  const int*   ei  = (const int*)d_in[14];

  if (ws_size < F_END * sizeof(float)) return;

  float* W     = (float*)d_ws;
  float* A1    = W + F_A1;
  short* Ac    = (short*)(W + F_SCR);
  float* A2    = W + F_A2;
  float* Ysc   = W + F_YSC;
  float* h0    = W + F_H0;
  float* h1    = W + F_H1;
  float* h2    = W + F_H2;
  float* u1b   = W + F_U1B;
  float* Yfsc  = W + F_YF;
  float* score = W + F_SCORE;
  float* gate1 = W + F_GATE1;
  float* gate2 = W + F_GATE2;
  float* dis1  = W + F_DIS1;
  float* dis2  = W + F_DIS2;
  int* perm1   = (int*)(W + F_PERM1);
  int* perm2   = (int*)(W + F_PERM2);
  int* inv1    = (int*)(W + F_INV1);
  int* inv2    = (int*)(W + F_INV2);
  int* cnt_in  = (int*)(W + F_CNTI);
  int* cnt_out = (int*)(W + F_CNTO);
  int* selfc   = (int*)(W + F_SELF);
  int* col_in  = (int*)(W + F_CI);
  int* col_out = (int*)(W + F_CO);
  int* csr_n   = (int*)(W + F_CSRN);
  int* csr_k   = (int*)(W + F_CSRK);
  float* csr_w = W + F_CSRW;
  float* out   = (float*)d_out;

  // ---- init (single fused fill) ----
  k_init<<<1024, 256, 0, stream>>>(A1, gate1, perm1, inv1, cnt_in, out + N0 * 3);

  // ---- edge lists ----
  k_count<<<(E0 + 255) / 256, 256, 0, stream>>>(ei, cnt_in, cnt_out, selfc, col_in, col_out);

  // ---- level 0 GCN + pool-1 score ----
  k_yw2<<<(N0 + BM - 1) / BM, 256, 0, stream>>>(x, nullptr, nullptr, 32, N0, N0, Wd0,
                                                nullptr, nullptr, nullptr, cnt_in, selfc, Ysc);
  k_gcn_sparse<<<N0, HID, 0, stream>>>(Ysc, cnt_in, col_in, selfc, bd0, p1, h0, score);
  k_topk<<<1, 256, 0, stream>>>(score, N0, K1N, perm1, gate1, inv1);

  // ---- A1 = augment(A0)[perm1][:,perm1]; CSR + dis1 ----
  k_pairs<<<N0, 128, 0, stream>>>(cnt_in, col_in, cnt_out, col_out, inv1, A1);
  k_a1csr<<<K1N, 128, 0, stream>>>(A1, csr_n, csr_k, csr_w, dis1);

  // ---- level 1 GCN (CSR spmv) + pool-2 score fused ----
  k_yw2<<<(K1N + BM - 1) / BM, 256, 0, stream>>>(h0, nullptr, nullptr, HID, N0, K1N, Wd1,
                                                 perm1, gate1, dis1, nullptr, nullptr, Ysc);
  k_spmv_csr<<<K1N, 128, 0, stream>>>(csr_n, csr_k, csr_w, Ysc, dis1, bd1, p2, h1, score, 1);
  k_topk<<<1, 256, 0, stream>>>(score, K1N, K2N, perm2, gate2, inv2);

  // ---- A2 = augment(A1)[perm2][:,perm2] (int16 Ac + CSR row + fused dis2) ----
  k_cmp<<<K1N, 256, 0, stream>>>(A1, perm2, Ac);
  k_sq2<<<K2N, 256, 0, stream>>>(A1, Ac, perm2, csr_n, csr_k, csr_w, A2, dis2);

  // ---- level 2 GCN (dense-scan spmv on A2) ----
  k_yw2<<<(K2N + BM - 1) / BM, 256, 0, stream>>>(h1, nullptr, nullptr, HID, K1N, K2N, Wd2,
                                                 perm2, gate2, dis2, nullptr, nullptr, Ysc);
  k_spmv<<<K2N, 128, 0, stream>>>(A2, K2N, LD2, Ysc, dis2, bd2, nullptr, h2, nullptr, 1);

  // ---- up path (combine fused into staging; CSR spmv) ----
  k_yw2<<<(K1N + BM - 1) / BM, 256, 0, stream>>>(h1, h2, inv2, HID, K1N, K1N, Wu0,
                                                 nullptr, nullptr, dis1, nullptr, nullptr, Ysc);
  k_spmv_csr<<<K1N, 128, 0, stream>>>(csr_n, csr_k, csr_w, Ysc, dis1, bu0, nullptr, u1b, nullptr, 1);

  // ---- final ----
  k_yf<<<N0, HID, 0, stream>>>(h0, u1b, inv1, Wu1, cnt_in, selfc, Yfsc);
  k_final<<<(N0 * 3 + 255) / 256, 256, 0, stream>>>(Yfsc, cnt_in, col_in, selfc, bu1, z, out);
}